// Round 5
// baseline (336.627 us; speedup 1.0000x reference)
//
#include <hip/hip_runtime.h>

#define NN 100000
#define NE 800000

typedef short bf16x8 __attribute__((ext_vector_type(8)));
typedef float f32x4 __attribute__((ext_vector_type(4)));

__device__ __forceinline__ float wave_reduce_sum(float v) {
    #pragma unroll
    for (int o = 32; o > 0; o >>= 1) v += __shfl_down(v, o, 64);
    return v; // valid in lane 0
}

__device__ __forceinline__ unsigned short f2bf(float f) {
    unsigned u = __float_as_uint(f);
    unsigned r = (u + 0x7FFFu + ((u >> 16) & 1u)) >> 16;
    return (unsigned short)r;
}
__device__ __forceinline__ float bf2f(unsigned short b) {
    return __uint_as_float(((unsigned)b) << 16);
}

// cb layout (floats): [0..27] vs1(k*4+h)  [28..55] vd1  [56..59] c1[h]  [60] c2
//                     [64..319] was2 = W2@as2   [320..575] wad2 = W2@ad2
__global__ void k_pre(const float* __restrict__ W1, const float* __restrict__ as1,
                      const float* __restrict__ ad1,
                      const float* __restrict__ We1, const float* __restrict__ ae1,
                      const float* __restrict__ We2, const float* __restrict__ ae2,
                      const float* __restrict__ W2, const float* __restrict__ as2,
                      const float* __restrict__ ad2,
                      float* __restrict__ cb, unsigned short* __restrict__ W2fr) {
    int t = threadIdx.x;
    if (blockIdx.x == 0) {
        if (t < 28) {
            int k = t >> 2, h = t & 3;
            float s = 0.f, d = 0.f;
            for (int c = 0; c < 64; ++c) {
                float w = W1[k * 256 + h * 64 + c];
                s += w * as1[h * 64 + c];
                d += w * ad1[h * 64 + c];
            }
            cb[t] = s; cb[28 + t] = d;
        } else if (t < 32) {
            int h = t - 28;
            float s = 0.f;
            for (int c = 0; c < 64; ++c) s += We1[h * 64 + c] * ae1[h * 64 + c];
            cb[56 + h] = s;
        } else if (t == 32) {
            float s = 0.f;
            for (int c = 0; c < 64; ++c) s += We2[c] * ae2[c];
            cb[60] = s;
        }
        float s = 0.f, d = 0.f;
        for (int j = 0; j < 64; ++j) {
            float w = W2[t * 64 + j];
            s += w * as2[j];
            d += w * ad2[j];
        }
        cb[64 + t] = s;
        cb[320 + t] = d;
    } else {
        int o = (blockIdx.x - 1) * 256 + t;        // 0..16383
        int i = o & 7, l = (o >> 3) & 63, ct = (o >> 9) & 3, ks = o >> 11;
        int k = ks * 32 + ((l >> 4) * 8) + i;
        int col = ct * 16 + (l & 15);
        W2fr[o] = f2bf(W2[k * 64 + col]);
    }
}

// per-node conv1 attention coefficients via folded 7x4 tables
__global__ void k_node1(const float* __restrict__ x, const float* __restrict__ cb,
                        float* __restrict__ a_src1, float* __restrict__ a_dst1) {
    int n = blockIdx.x * 256 + threadIdx.x;
    if (n >= NN) return;
    float xv[7];
    #pragma unroll
    for (int k = 0; k < 7; ++k) xv[k] = x[n * 7 + k];
    float s[4] = {0.f, 0.f, 0.f, 0.f}, d[4] = {0.f, 0.f, 0.f, 0.f};
    #pragma unroll
    for (int k = 0; k < 7; ++k)
        #pragma unroll
        for (int h = 0; h < 4; ++h) {
            s[h] += xv[k] * cb[k * 4 + h];
            d[h] += xv[k] * cb[28 + k * 4 + h];
        }
    *(float4*)(a_src1 + n * 4) = make_float4(s[0], s[1], s[2], s[3]);
    *(float4*)(a_dst1 + n * 4) = make_float4(d[0], d[1], d[2], d[3]);
}

__global__ void k_hist(const int* __restrict__ dst, int* __restrict__ hist) {
    int e0 = (blockIdx.x * 256 + threadIdx.x) * 4;
    if (e0 >= NE) return;
    int4 d = *(const int4*)(dst + e0);
    atomicAdd(&hist[d.x], 1);
    atomicAdd(&hist[d.y], 1);
    atomicAdd(&hist[d.z], 1);
    atomicAdd(&hist[d.w], 1);
}

// --- 3-phase parallel exclusive scan over hist[NN] -> offs[NN+1], cursor[NN] ---
__global__ __launch_bounds__(1024) void k_scanA(const int* __restrict__ hist,
                                                int* __restrict__ bsum) {
    __shared__ int ws[16];
    int i = blockIdx.x * 1024 + threadIdx.x;
    int lane = threadIdx.x & 63, wid = threadIdx.x >> 6;
    int v = (i < NN) ? hist[i] : 0;
    #pragma unroll
    for (int o = 32; o; o >>= 1) v += __shfl_down(v, o, 64);
    if (lane == 0) ws[wid] = v;
    __syncthreads();
    if (wid == 0) {
        int u = (lane < 16) ? ws[lane] : 0;
        #pragma unroll
        for (int o = 8; o; o >>= 1) u += __shfl_down(u, o, 64);
        if (lane == 0) bsum[blockIdx.x] = u;
    }
}

__global__ void k_scanB(const int* __restrict__ bsum, int* __restrict__ bexcl) {
    __shared__ int w0tot;
    int t = threadIdx.x, lane = t & 63, wid = t >> 6;
    int v = (t < 98) ? bsum[t] : 0;
    int s = v;
    #pragma unroll
    for (int d = 1; d < 64; d <<= 1) { int u = __shfl_up(s, d, 64); if (lane >= d) s += u; }
    if (t == 63) w0tot = s;
    __syncthreads();
    if (wid == 1) s += w0tot;
    if (t < 98) bexcl[t] = s - v;
}

__global__ __launch_bounds__(1024) void k_scanC(const int* __restrict__ hist,
                                                const int* __restrict__ bexcl,
                                                int* __restrict__ offs,
                                                int* __restrict__ cursor) {
    __shared__ int ws[16];
    int b = blockIdx.x;
    int i = b * 1024 + threadIdx.x;
    int lane = threadIdx.x & 63, wid = threadIdx.x >> 6;
    int v = (i < NN) ? hist[i] : 0;
    int s = v;
    #pragma unroll
    for (int d = 1; d < 64; d <<= 1) { int u = __shfl_up(s, d, 64); if (lane >= d) s += u; }
    if (lane == 63) ws[wid] = s;
    __syncthreads();
    if (wid == 0) {
        int u2 = (lane < 16) ? ws[lane] : 0;
        #pragma unroll
        for (int d = 1; d < 16; d <<= 1) { int uu = __shfl_up(u2, d, 64); if (lane >= d) u2 += uu; }
        if (lane < 16) ws[lane] = u2;
    }
    __syncthreads();
    int incl = s + (wid ? ws[wid - 1] : 0) + bexcl[b];
    if (i < NN) { offs[i + 1] = incl; cursor[i] = incl - v; }
    if (i == 0) offs[0] = 0;
}

// minimal scatter: sorted position + packed (src, ea)
__global__ void k_scatter(const int* __restrict__ src, const int* __restrict__ dst,
                          const float* __restrict__ ea,
                          int* __restrict__ cursor, int2* __restrict__ es_se) {
    int e = blockIdx.x * 256 + threadIdx.x;
    if (e >= NE) return;
    int d = dst[e];
    int pos = atomicAdd(&cursor[d], 1);
    es_se[pos] = make_int2(src[e], __float_as_int(ea[e]));
}

// node-run edge expansion: conv1 weights (exp of logits) + x[src] row (padded w/ 1.0)
// 8 lanes per node; writes are run-coalesced (128B/256B chunks).
__global__ __launch_bounds__(256) void k_edges(
    const float* __restrict__ x, const int2* __restrict__ es_se,
    const int* __restrict__ offs,
    const float* __restrict__ a_src1, const float* __restrict__ a_dst1,
    const float* __restrict__ cb,
    float* __restrict__ es_w, float* __restrict__ es_x8) {
    int t = threadIdx.x, lane = t & 63, wid = t >> 6;
    int g = lane >> 3, q = lane & 7;
    int n = (blockIdx.x * 4 + wid) * 8 + g;
    int o0 = offs[n], o1 = offs[n + 1];
    float4 ad_ = *(const float4*)(a_dst1 + n * 4);
    float c56 = cb[56], c57 = cb[57], c58 = cb[58], c59 = cb[59];
    for (int j = o0 + q; j < o1; j += 8) {
        int2 se = es_se[j];
        int s = se.x;
        float eav = __int_as_float(se.y);
        float4 as_ = *(const float4*)(a_src1 + s * 4);
        float xv[7];
        #pragma unroll
        for (int k = 0; k < 7; ++k) xv[k] = x[s * 7 + k];
        float lg0 = as_.x + ad_.x + eav * c56;
        float lg1 = as_.y + ad_.y + eav * c57;
        float lg2 = as_.z + ad_.z + eav * c58;
        float lg3 = as_.w + ad_.w + eav * c59;
        lg0 = lg0 >= 0.f ? lg0 : 0.2f * lg0;
        lg1 = lg1 >= 0.f ? lg1 : 0.2f * lg1;
        lg2 = lg2 >= 0.f ? lg2 : 0.2f * lg2;
        lg3 = lg3 >= 0.f ? lg3 : 0.2f * lg3;
        *(float4*)(es_w + j * 4) =
            make_float4(__expf(lg0), __expf(lg1), __expf(lg2), __expf(lg3));
        *(float4*)(es_x8 + j * 8) = make_float4(xv[0], xv[1], xv[2], xv[3]);
        *(float4*)(es_x8 + j * 8 + 4) = make_float4(xv[4], xv[5], xv[6], 1.f);
    }
}

// fused: conv1 reduce (streaming, lane=(edge slot, channel)) -> h -> a_src2/a_dst2
//        -> MFMA h@W2 -> xh2 bf16
__global__ __launch_bounds__(256) void k_conv1red(
    const float* __restrict__ W1, const float* __restrict__ b1,
    const float* __restrict__ cb, const int* __restrict__ offs,
    const float* __restrict__ es_x8, const float* __restrict__ es_w,
    const unsigned short* __restrict__ W2fr,
    unsigned short* __restrict__ xh2b, float* __restrict__ a_src2, float* __restrict__ a_dst2) {
    __shared__ __attribute__((aligned(16))) unsigned short hs[16][264];
    int t = threadIdx.x, lane = t & 63, wid = t >> 6;
    float w1r[7][4], b1r[4], was2r[4], wad2r[4];
    #pragma unroll
    for (int k = 0; k < 7; ++k)
        #pragma unroll
        for (int h = 0; h < 4; ++h) w1r[k][h] = W1[k * 256 + h * 64 + lane];
    #pragma unroll
    for (int h = 0; h < 4; ++h) {
        b1r[h] = b1[h * 64 + lane];
        was2r[h] = cb[64 + h * 64 + lane];
        wad2r[h] = cb[320 + h * 64 + lane];
    }
    int e8 = lane >> 3;
    int n0 = blockIdx.x * 16;
    for (int nl = 0; nl < 4; ++nl) {
        int n = n0 + wid * 4 + nl;
        int o0 = offs[n], o1 = offs[n + 1];
        float mh[4] = {0.f, 0.f, 0.f, 0.f};
        for (int j = o0; j < o1; j += 8) {
            float xl = es_x8[j * 8 + lane];                     // coalesced 256B
            float wl = 0.f;
            if (lane < 32 && j + (lane >> 2) < o1) wl = es_w[j * 4 + lane];
            mh[0] = fmaf(__shfl(wl, e8 * 4 + 0, 64), xl, mh[0]);
            mh[1] = fmaf(__shfl(wl, e8 * 4 + 1, 64), xl, mh[1]);
            mh[2] = fmaf(__shfl(wl, e8 * 4 + 2, 64), xl, mh[2]);
            mh[3] = fmaf(__shfl(wl, e8 * 4 + 3, 64), xl, mh[3]);
        }
        // reduce over 8 edge slots (lane bits 3..5); after this every lane
        // holds m[h][c] for its channel class c = lane&7 (z lives at c=7)
        #pragma unroll
        for (int h = 0; h < 4; ++h) {
            mh[h] += __shfl_xor(mh[h], 8, 64);
            mh[h] += __shfl_xor(mh[h], 16, 64);
            mh[h] += __shfl_xor(mh[h], 32, 64);
        }
        bool has = o1 > o0;
        float ps = 0.f, pd = 0.f;
        #pragma unroll
        for (int h = 0; h < 4; ++h) {
            float z = __shfl(mh[h], 7, 64);
            float a = 0.f;
            #pragma unroll
            for (int k = 0; k < 7; ++k) a = fmaf(__shfl(mh[h], k, 64), w1r[k][h], a);
            float mm = (has ? a / z : 0.f) + b1r[h];
            float hv = mm > 0.f ? mm : (__expf(mm) - 1.f);
            ps += hv * was2r[h];
            pd += hv * wad2r[h];
            hs[wid * 4 + nl][h * 64 + lane] = f2bf(hv);
        }
        ps = wave_reduce_sum(ps);
        pd = wave_reduce_sum(pd);
        if (lane == 0) { a_src2[n] = ps; a_dst2[n] = pd; }
    }
    __syncthreads();
    // MFMA: xh2[16 nodes][64 ch]; wave wid owns column tile wid*16..+16
    f32x4 acc = {0.f, 0.f, 0.f, 0.f};
    int row = lane & 15, kg = lane >> 4;
    #pragma unroll
    for (int ks = 0; ks < 8; ++ks) {
        bf16x8 av = *(const bf16x8*)&hs[row][ks * 32 + kg * 8];
        bf16x8 bv = *(const bf16x8*)(W2fr + (((ks * 4 + wid) * 64) + lane) * 8);
        acc = __builtin_amdgcn_mfma_f32_16x16x32_bf16(av, bv, acc, 0, 0, 0);
    }
    #pragma unroll
    for (int i = 0; i < 4; ++i) {
        int r = kg * 4 + i;
        xh2b[(n0 + r) * 64 + wid * 16 + row] = f2bf(acc[i]);
    }
}

// conv2 normalization + per-source cluster coefficient table.
// pass1: ew = exp(leaky(logit)) -> es_ew (coalesced) + z reduce
// pass2: atomicAdd cs[src][cluster(dst)] += ew/z
__global__ __launch_bounds__(256) void k_znorm(
    const int2* __restrict__ es_se, const int* __restrict__ offs,
    const float* __restrict__ a_src2, const float* __restrict__ a_dst2,
    const int* __restrict__ assign, const float* __restrict__ cb,
    float* __restrict__ es_ew, float* __restrict__ cs) {
    int t = threadIdx.x, lane = t & 63, wid = t >> 6;
    int g = lane >> 3, q = lane & 7;
    int n = (blockIdx.x * 4 + wid) * 8 + g;
    int o0 = offs[n], o1 = offs[n + 1];
    float adn = a_dst2[n];
    float c2 = cb[60];
    float z = 0.f;
    for (int j = o0 + q; j < o1; j += 8) {
        int2 se = es_se[j];
        float lg = a_src2[se.x] + adn + __int_as_float(se.y) * c2;
        lg = lg >= 0.f ? lg : 0.2f * lg;
        float ew = __expf(lg);
        es_ew[j] = ew;
        z += ew;
    }
    z += __shfl_xor(z, 1, 64);
    z += __shfl_xor(z, 2, 64);
    z += __shfl_xor(z, 4, 64);
    float rz = 1.f / z;          // no edges -> loop below doesn't run
    int c = assign[n];
    for (int j = o0 + q; j < o1; j += 8) {
        int sx = es_se[j].x;
        atomicAdd(&cs[sx * 4 + c], es_ew[j] * rz);
    }
}

// coalesced pooling: cluster_sum[c][j] = sum_n cs[n][c] * xh2[n][j]; + counts/cf
__global__ __launch_bounds__(256) void k_pool(
    const unsigned short* __restrict__ xh2b, const float* __restrict__ cs,
    const int* __restrict__ assign, const float* __restrict__ x,
    float* __restrict__ gacc) {
    __shared__ float csum[264];
    int t = threadIdx.x, lane = t & 63, wid = t >> 6;
    for (int i = t; i < 264; i += 256) csum[i] = 0.f;
    __syncthreads();
    float f0 = 0.f, f1 = 0.f, f2 = 0.f, f3 = 0.f;
    float cnt = 0.f, cf = 0.f;
    int nw = gridDim.x * 4;
    for (int n = blockIdx.x * 4 + wid; n < NN; n += nw) {
        float v = bf2f(xh2b[n * 64 + lane]);
        float4 c4 = *(const float4*)(cs + n * 4);
        f0 = fmaf(c4.x, v, f0);
        f1 = fmaf(c4.y, v, f1);
        f2 = fmaf(c4.z, v, f2);
        f3 = fmaf(c4.w, v, f3);
        if (lane < 4) {
            int a = assign[n];
            if (a == lane) { cnt += 1.f; cf += x[n * 7 + 6]; }
        }
    }
    atomicAdd(&csum[0 * 64 + lane], f0);
    atomicAdd(&csum[1 * 64 + lane], f1);
    atomicAdd(&csum[2 * 64 + lane], f2);
    atomicAdd(&csum[3 * 64 + lane], f3);
    if (lane < 4) {
        atomicAdd(&csum[256 + lane], cnt);
        atomicAdd(&csum[260 + lane], cf);
    }
    __syncthreads();
    for (int i = t; i < 264; i += 256) atomicAdd(&gacc[i], csum[i]);
}

// final head: cluster means (+cnt*b2), actor MLP + softmax, critic MLP
__global__ void k_head(const float* __restrict__ gacc, const float* __restrict__ b2,
                       const float* __restrict__ A1, const float* __restrict__ ba1,
                       const float* __restrict__ A2, const float* __restrict__ ba2,
                       const float* __restrict__ C1, const float* __restrict__ bc1,
                       const float* __restrict__ C2, const float* __restrict__ bc2,
                       float* __restrict__ out) {
    __shared__ float zc[4][64];
    __shared__ float cfs[4];
    __shared__ float logits[4];
    int j = threadIdx.x; // 64
    float b2j = b2[j];
    #pragma unroll
    for (int c = 0; c < 4; ++c) {
        float cnt = gacc[256 + c];
        float den = fmaxf(cnt, 1.f);
        zc[c][j] = (cnt > 0.f) ? (gacc[c * 64 + j] + cnt * b2j) / den : 0.f;
        if (j == 0) cfs[c] = (cnt > 0.f) ? gacc[260 + c] / den : 0.f;
    }
    __syncthreads();
    #pragma unroll
    for (int c = 0; c < 4; ++c) {
        float tv = ba1[j];
        for (int k = 0; k < 64; ++k) tv += zc[c][k] * A1[k * 64 + j];
        tv += cfs[c] * A1[64 * 64 + j];
        tv = fmaxf(tv, 0.f);
        float s = wave_reduce_sum(tv * A2[j]);
        if (j == 0) logits[c] = s + ba2[0];
    }
    float vj = bc1[j];
    for (int k = 0; k < 256; ++k) vj += zc[k >> 6][k & 63] * C1[k * 64 + j];
    vj = fmaxf(vj, 0.f);
    float v = wave_reduce_sum(vj * C2[j]);
    __syncthreads();
    if (j == 0) {
        float m = fmaxf(fmaxf(logits[0], logits[1]), fmaxf(logits[2], logits[3]));
        float e0 = __expf(logits[0] - m), e1 = __expf(logits[1] - m);
        float e2 = __expf(logits[2] - m), e3 = __expf(logits[3] - m);
        float sum = e0 + e1 + e2 + e3;
        out[0] = e0 / sum; out[1] = e1 / sum; out[2] = e2 / sum; out[3] = e3 / sum;
        out[4] = v + bc2[0];
    }
    #pragma unroll
    for (int c = 0; c < 4; ++c) out[5 + c * 64 + j] = zc[c][j];
}

extern "C" void kernel_launch(void* const* d_in, const int* in_sizes, int n_in,
                              void* d_out, int out_size, void* d_ws, size_t ws_size,
                              hipStream_t stream) {
    const float* x    = (const float*)d_in[0];
    const int*   ei   = (const int*)d_in[1];
    const float* ea   = (const float*)d_in[2];
    const int*   asg  = (const int*)d_in[3];
    const float* W1   = (const float*)d_in[4];
    const float* as1  = (const float*)d_in[5];
    const float* ad1  = (const float*)d_in[6];
    const float* We1  = (const float*)d_in[7];
    const float* ae1  = (const float*)d_in[8];
    const float* b1   = (const float*)d_in[9];
    const float* W2   = (const float*)d_in[10];
    const float* as2  = (const float*)d_in[11];
    const float* ad2  = (const float*)d_in[12];
    const float* We2  = (const float*)d_in[13];
    const float* ae2  = (const float*)d_in[14];
    const float* b2   = (const float*)d_in[15];
    const float* A1   = (const float*)d_in[16];
    const float* ba1  = (const float*)d_in[17];
    const float* A2   = (const float*)d_in[18];
    const float* ba2  = (const float*)d_in[19];
    const float* C1   = (const float*)d_in[20];
    const float* bc1  = (const float*)d_in[21];
    const float* C2   = (const float*)d_in[22];
    const float* bc2  = (const float*)d_in[23];
    const int* src = ei;
    const int* dst = ei + NE;

    char* w = (char*)d_ws;
    size_t off = 0;
    auto alloc = [&](size_t bytes) -> void* {
        void* p = w + off;
        off += (bytes + 255) & ~(size_t)255;
        return p;
    };
    float* a_src1 = (float*)alloc(NN * 4 * sizeof(float));
    float* a_dst1 = (float*)alloc(NN * 4 * sizeof(float));
    float* a_src2 = (float*)alloc(NN * sizeof(float));
    float* a_dst2 = (float*)alloc(NN * sizeof(float));
    int*   hist   = (int*)alloc(NN * sizeof(int));
    int*   offs   = (int*)alloc((NN + 1) * sizeof(int));
    int*   cursor = (int*)alloc(NN * sizeof(int));
    int*   bsum   = (int*)alloc(128 * sizeof(int));
    int*   bexcl  = (int*)alloc(128 * sizeof(int));
    int2*  es_se  = (int2*)alloc(NE * sizeof(int2));
    float* es_w   = (float*)alloc((NE * 4 + 64) * sizeof(float));
    float* es_x8  = (float*)alloc((NE * 8 + 64) * sizeof(float));
    float* es_ew  = (float*)alloc(NE * sizeof(float));
    float* cs     = (float*)alloc(NN * 4 * sizeof(float));
    unsigned short* xh2b = (unsigned short*)alloc(NN * 64 * sizeof(unsigned short));
    unsigned short* W2fr = (unsigned short*)alloc(16384 * sizeof(unsigned short));
    float* cb     = (float*)alloc(576 * sizeof(float));
    float* gacc   = (float*)alloc(264 * sizeof(float));
    (void)ws_size; (void)n_in; (void)in_sizes; (void)out_size;

    hipMemsetAsync(hist, 0, NN * sizeof(int), stream);
    hipMemsetAsync(cs, 0, NN * 4 * sizeof(float), stream);
    hipMemsetAsync(gacc, 0, 264 * sizeof(float), stream);

    k_pre<<<65, 256, 0, stream>>>(W1, as1, ad1, We1, ae1, We2, ae2, W2, as2, ad2, cb, W2fr);
    k_node1<<<(NN + 255) / 256, 256, 0, stream>>>(x, cb, a_src1, a_dst1);
    k_hist<<<(NE / 4 + 255) / 256, 256, 0, stream>>>(dst, hist);
    k_scanA<<<98, 1024, 0, stream>>>(hist, bsum);
    k_scanB<<<1, 128, 0, stream>>>(bsum, bexcl);
    k_scanC<<<98, 1024, 0, stream>>>(hist, bexcl, offs, cursor);
    k_scatter<<<(NE + 255) / 256, 256, 0, stream>>>(src, dst, ea, cursor, es_se);
    k_edges<<<NN / 32, 256, 0, stream>>>(x, es_se, offs, a_src1, a_dst1, cb, es_w, es_x8);
    k_conv1red<<<NN / 16, 256, 0, stream>>>(W1, b1, cb, offs, es_x8, es_w, W2fr,
                                            xh2b, a_src2, a_dst2);
    k_znorm<<<NN / 32, 256, 0, stream>>>(es_se, offs, a_src2, a_dst2, asg, cb, es_ew, cs);
    k_pool<<<256, 256, 0, stream>>>(xh2b, cs, asg, x, gacc);
    k_head<<<1, 64, 0, stream>>>(gacc, b2, A1, ba1, A2, ba2, C1, bc1, C2, bc2, (float*)d_out);
}

// Round 6
// 326.234 us; speedup vs baseline: 1.0319x; 1.0319x over previous
//
#include <hip/hip_runtime.h>

#define NN 100000
#define NE 800000

typedef short bf16x8 __attribute__((ext_vector_type(8)));
typedef float f32x4 __attribute__((ext_vector_type(4)));

__device__ __forceinline__ float wave_reduce_sum(float v) {
    #pragma unroll
    for (int o = 32; o > 0; o >>= 1) v += __shfl_down(v, o, 64);
    return v; // valid in lane 0
}

__device__ __forceinline__ unsigned short f2bf(float f) {
    unsigned u = __float_as_uint(f);
    unsigned r = (u + 0x7FFFu + ((u >> 16) & 1u)) >> 16;
    return (unsigned short)r;
}
__device__ __forceinline__ float bf2f(unsigned short b) {
    return __uint_as_float(((unsigned)b) << 16);
}

// cb layout (floats): [0..27] vs1(k*4+h)  [28..55] vd1  [56..59] c1[h]  [60] c2
//                     [64..319] was2 = W2@as2   [320..575] wad2 = W2@ad2
__global__ void k_pre(const float* __restrict__ W1, const float* __restrict__ as1,
                      const float* __restrict__ ad1,
                      const float* __restrict__ We1, const float* __restrict__ ae1,
                      const float* __restrict__ We2, const float* __restrict__ ae2,
                      const float* __restrict__ W2, const float* __restrict__ as2,
                      const float* __restrict__ ad2,
                      float* __restrict__ cb, unsigned short* __restrict__ W2fr) {
    int t = threadIdx.x;
    if (blockIdx.x == 0) {
        if (t < 28) {
            int k = t >> 2, h = t & 3;
            float s = 0.f, d = 0.f;
            for (int c = 0; c < 64; ++c) {
                float w = W1[k * 256 + h * 64 + c];
                s += w * as1[h * 64 + c];
                d += w * ad1[h * 64 + c];
            }
            cb[t] = s; cb[28 + t] = d;
        } else if (t < 32) {
            int h = t - 28;
            float s = 0.f;
            for (int c = 0; c < 64; ++c) s += We1[h * 64 + c] * ae1[h * 64 + c];
            cb[56 + h] = s;
        } else if (t == 32) {
            float s = 0.f;
            for (int c = 0; c < 64; ++c) s += We2[c] * ae2[c];
            cb[60] = s;
        }
        float s = 0.f, d = 0.f;
        for (int j = 0; j < 64; ++j) {
            float w = W2[t * 64 + j];
            s += w * as2[j];
            d += w * ad2[j];
        }
        cb[64 + t] = s;
        cb[320 + t] = d;
    } else {
        int o = (blockIdx.x - 1) * 256 + t;        // 0..16383
        int i = o & 7, l = (o >> 3) & 63, ct = (o >> 9) & 3, ks = o >> 11;
        int k = ks * 32 + ((l >> 4) * 8) + i;
        int col = ct * 16 + (l & 15);
        W2fr[o] = f2bf(W2[k * 64 + col]);
    }
}

// per-node conv1 attention coefficients via folded 7x4 tables
__global__ void k_node1(const float* __restrict__ x, const float* __restrict__ cb,
                        float* __restrict__ a_src1, float* __restrict__ a_dst1) {
    int n = blockIdx.x * 256 + threadIdx.x;
    if (n >= NN) return;
    float xv[7];
    #pragma unroll
    for (int k = 0; k < 7; ++k) xv[k] = x[n * 7 + k];
    float s[4] = {0.f, 0.f, 0.f, 0.f}, d[4] = {0.f, 0.f, 0.f, 0.f};
    #pragma unroll
    for (int k = 0; k < 7; ++k)
        #pragma unroll
        for (int h = 0; h < 4; ++h) {
            s[h] += xv[k] * cb[k * 4 + h];
            d[h] += xv[k] * cb[28 + k * 4 + h];
        }
    *(float4*)(a_src1 + n * 4) = make_float4(s[0], s[1], s[2], s[3]);
    *(float4*)(a_dst1 + n * 4) = make_float4(d[0], d[1], d[2], d[3]);
}

__global__ void k_hist(const int* __restrict__ dst, int* __restrict__ hist) {
    int e0 = (blockIdx.x * 256 + threadIdx.x) * 4;
    if (e0 >= NE) return;
    int4 d = *(const int4*)(dst + e0);
    atomicAdd(&hist[d.x], 1);
    atomicAdd(&hist[d.y], 1);
    atomicAdd(&hist[d.z], 1);
    atomicAdd(&hist[d.w], 1);
}

// --- 3-phase parallel exclusive scan over hist[NN] -> offs[NN+1], cursor[NN] ---
__global__ __launch_bounds__(1024) void k_scanA(const int* __restrict__ hist,
                                                int* __restrict__ bsum) {
    __shared__ int ws[16];
    int i = blockIdx.x * 1024 + threadIdx.x;
    int lane = threadIdx.x & 63, wid = threadIdx.x >> 6;
    int v = (i < NN) ? hist[i] : 0;
    #pragma unroll
    for (int o = 32; o; o >>= 1) v += __shfl_down(v, o, 64);
    if (lane == 0) ws[wid] = v;
    __syncthreads();
    if (wid == 0) {
        int u = (lane < 16) ? ws[lane] : 0;
        #pragma unroll
        for (int o = 8; o; o >>= 1) u += __shfl_down(u, o, 64);
        if (lane == 0) bsum[blockIdx.x] = u;
    }
}

__global__ void k_scanB(const int* __restrict__ bsum, int* __restrict__ bexcl) {
    __shared__ int w0tot;
    int t = threadIdx.x, lane = t & 63, wid = t >> 6;
    int v = (t < 98) ? bsum[t] : 0;
    int s = v;
    #pragma unroll
    for (int d = 1; d < 64; d <<= 1) { int u = __shfl_up(s, d, 64); if (lane >= d) s += u; }
    if (t == 63) w0tot = s;
    __syncthreads();
    if (wid == 1) s += w0tot;
    if (t < 98) bexcl[t] = s - v;
}

__global__ __launch_bounds__(1024) void k_scanC(const int* __restrict__ hist,
                                                const int* __restrict__ bexcl,
                                                int* __restrict__ offs,
                                                int* __restrict__ cursor) {
    __shared__ int ws[16];
    int b = blockIdx.x;
    int i = b * 1024 + threadIdx.x;
    int lane = threadIdx.x & 63, wid = threadIdx.x >> 6;
    int v = (i < NN) ? hist[i] : 0;
    int s = v;
    #pragma unroll
    for (int d = 1; d < 64; d <<= 1) { int u = __shfl_up(s, d, 64); if (lane >= d) s += u; }
    if (lane == 63) ws[wid] = s;
    __syncthreads();
    if (wid == 0) {
        int u2 = (lane < 16) ? ws[lane] : 0;
        #pragma unroll
        for (int d = 1; d < 16; d <<= 1) { int uu = __shfl_up(u2, d, 64); if (lane >= d) u2 += uu; }
        if (lane < 16) ws[lane] = u2;
    }
    __syncthreads();
    int incl = s + (wid ? ws[wid - 1] : 0) + bexcl[b];
    if (i < NN) { offs[i + 1] = incl; cursor[i] = incl - v; }
    if (i == 0) offs[0] = 0;
}

// minimal scatter: sorted position + packed (src, ea)
__global__ void k_scatter(const int* __restrict__ src, const int* __restrict__ dst,
                          const float* __restrict__ ea,
                          int* __restrict__ cursor, int2* __restrict__ es_se) {
    int e = blockIdx.x * 256 + threadIdx.x;
    if (e >= NE) return;
    int d = dst[e];
    int pos = atomicAdd(&cursor[d], 1);
    es_se[pos] = make_int2(src[e], __float_as_int(ea[e]));
}

// fused conv1: two-phase LDS-staged segmented reduce -> h -> a_src2/a_dst2 -> MFMA -> xh2 bf16
// block = 32 nodes, 256 threads.
// phase 1 (edge-parallel): stage {x8[src], w[4]=exp(leaky(logit))} for a 256-edge chunk into LDS.
// phase 2 (8 lanes/node): m[h][k] += w[h]*x8[k] purely from LDS.
__global__ __launch_bounds__(256) void k_conv1red(
    const float* __restrict__ x, const float* __restrict__ W1, const float* __restrict__ b1,
    const float* __restrict__ cb, const int* __restrict__ offs,
    const int2* __restrict__ es_se,
    const float* __restrict__ a_src1, const float* __restrict__ a_dst1,
    const unsigned short* __restrict__ W2fr,
    unsigned short* __restrict__ xh2b, float* __restrict__ a_src2, float* __restrict__ a_dst2) {
    __shared__ int soffs[33];
    __shared__ float4 ad1L[32];
    __shared__ float xw[256][13];
    __shared__ float ms[32][33];
    __shared__ __attribute__((aligned(16))) unsigned short hs[32][264];
    int t = threadIdx.x, lane = t & 63, wid = t >> 6;
    int n0 = blockIdx.x * 32;
    if (t <= 32) soffs[t] = offs[n0 + t];
    if (t < 32) ad1L[t] = *(const float4*)(a_dst1 + (n0 + t) * 4);
    // finish-phase constants (lane = channel)
    float w1r[7][4], b1r[4], was2r[4], wad2r[4];
    #pragma unroll
    for (int k = 0; k < 7; ++k)
        #pragma unroll
        for (int h = 0; h < 4; ++h) w1r[k][h] = W1[k * 256 + h * 64 + lane];
    #pragma unroll
    for (int h = 0; h < 4; ++h) {
        b1r[h] = b1[h * 64 + lane];
        was2r[h] = cb[64 + h * 64 + lane];
        wad2r[h] = cb[320 + h * 64 + lane];
    }
    float c56 = cb[56], c57 = cb[57], c58 = cb[58], c59 = cb[59];
    __syncthreads();
    int E0 = soffs[0], E1 = soffs[32];
    int g = t >> 3, q = t & 7;
    int go0 = soffs[g], go1 = soffs[g + 1];
    float mh0 = 0.f, mh1 = 0.f, mh2 = 0.f, mh3 = 0.f;
    for (int C0 = E0; C0 < E1; C0 += 256) {
        int C1 = min(C0 + 256, E1);
        int j = C0 + t;
        if (j < C1) {
            int2 se = es_se[j];
            int s = se.x;
            float eav = __int_as_float(se.y);
            int g2 = 0;
            #pragma unroll
            for (int st = 16; st; st >>= 1)
                if (soffs[g2 + st] <= j) g2 += st;
            float4 as_ = *(const float4*)(a_src1 + s * 4);
            float4 ad_ = ad1L[g2];
            float lg0 = as_.x + ad_.x + eav * c56;
            float lg1 = as_.y + ad_.y + eav * c57;
            float lg2 = as_.z + ad_.z + eav * c58;
            float lg3 = as_.w + ad_.w + eav * c59;
            lg0 = lg0 >= 0.f ? lg0 : 0.2f * lg0;
            lg1 = lg1 >= 0.f ? lg1 : 0.2f * lg1;
            lg2 = lg2 >= 0.f ? lg2 : 0.2f * lg2;
            lg3 = lg3 >= 0.f ? lg3 : 0.2f * lg3;
            const float* xp = x + s * 7;
            xw[t][0] = xp[0]; xw[t][1] = xp[1]; xw[t][2] = xp[2]; xw[t][3] = xp[3];
            xw[t][4] = xp[4]; xw[t][5] = xp[5]; xw[t][6] = xp[6]; xw[t][7] = 1.f;
            xw[t][8] = __expf(lg0); xw[t][9] = __expf(lg1);
            xw[t][10] = __expf(lg2); xw[t][11] = __expf(lg3);
        }
        __syncthreads();
        int lo = max(go0, C0) - C0, hi = min(go1, C1) - C0;
        for (int jj = lo; jj < hi; ++jj) {
            float xv = xw[jj][q];
            mh0 = fmaf(xw[jj][8], xv, mh0);
            mh1 = fmaf(xw[jj][9], xv, mh1);
            mh2 = fmaf(xw[jj][10], xv, mh2);
            mh3 = fmaf(xw[jj][11], xv, mh3);
        }
        __syncthreads();
    }
    ms[g][0 * 8 + q] = mh0; ms[g][1 * 8 + q] = mh1;
    ms[g][2 * 8 + q] = mh2; ms[g][3 * 8 + q] = mh3;
    __syncthreads();
    // finish: wave wid processes nodes wid*8 .. wid*8+7 (lane = channel)
    for (int gi = wid * 8; gi < wid * 8 + 8; ++gi) {
        int n = n0 + gi;
        bool has = soffs[gi + 1] > soffs[gi];
        float ps = 0.f, pd = 0.f;
        #pragma unroll
        for (int h = 0; h < 4; ++h) {
            float z = ms[gi][h * 8 + 7];
            float a = 0.f;
            #pragma unroll
            for (int k = 0; k < 7; ++k) a = fmaf(ms[gi][h * 8 + k], w1r[k][h], a);
            float mm = (has ? a / z : 0.f) + b1r[h];
            float hv = mm > 0.f ? mm : (__expf(mm) - 1.f);
            ps += hv * was2r[h];
            pd += hv * wad2r[h];
            hs[gi][h * 64 + lane] = f2bf(hv);
        }
        ps = wave_reduce_sum(ps);
        pd = wave_reduce_sum(pd);
        if (lane == 0) { a_src2[n] = ps; a_dst2[n] = pd; }
    }
    __syncthreads();
    // MFMA: 2 node-tiles x 4 col-tiles = 8 units over 4 waves
    int row = lane & 15, kg = lane >> 4;
    #pragma unroll
    for (int u = wid; u < 8; u += 4) {
        int nt = u & 1, ct = u >> 1;
        f32x4 acc = {0.f, 0.f, 0.f, 0.f};
        #pragma unroll
        for (int ks = 0; ks < 8; ++ks) {
            bf16x8 av = *(const bf16x8*)&hs[nt * 16 + row][ks * 32 + kg * 8];
            bf16x8 bv = *(const bf16x8*)(W2fr + (((ks * 4 + ct) * 64) + lane) * 8);
            acc = __builtin_amdgcn_mfma_f32_16x16x32_bf16(av, bv, acc, 0, 0, 0);
        }
        #pragma unroll
        for (int i = 0; i < 4; ++i)
            xh2b[(n0 + nt * 16 + kg * 4 + i) * 64 + ct * 16 + row] = f2bf(acc[i]);
    }
}

// conv2 pass A (original edge order, fully coalesced + L2 gathers):
// ew = exp(leaky(logit)), z1[dst] += ew
__global__ void k_zA(const int* __restrict__ src, const int* __restrict__ dst,
                     const float* __restrict__ ea,
                     const float* __restrict__ a_src2, const float* __restrict__ a_dst2,
                     const float* __restrict__ cb,
                     float* __restrict__ ew_o, float* __restrict__ z1) {
    int e = blockIdx.x * 256 + threadIdx.x;
    if (e >= NE) return;
    int d = dst[e];
    float lg = a_src2[src[e]] + a_dst2[d] + ea[e] * cb[60];
    lg = lg >= 0.f ? lg : 0.2f * lg;
    float ew = __expf(lg);
    ew_o[e] = ew;
    atomicAdd(&z1[d], ew);
}

// conv2 pass B: cs[src][cluster(dst)] += ew / z1[dst]
__global__ void k_zB(const int* __restrict__ src, const int* __restrict__ dst,
                     const float* __restrict__ ew_o, const float* __restrict__ z1,
                     const int* __restrict__ assign, float* __restrict__ cs) {
    int e = blockIdx.x * 256 + threadIdx.x;
    if (e >= NE) return;
    int d = dst[e];
    float rz = 1.f / z1[d];
    int c = assign[d];
    atomicAdd(&cs[src[e] * 4 + c], ew_o[e] * rz);
}

// coalesced pooling: cluster_sum[c][j] = sum_n cs[n][c] * xh2[n][j]; + counts/cf
__global__ __launch_bounds__(256) void k_pool(
    const unsigned short* __restrict__ xh2b, const float* __restrict__ cs,
    const int* __restrict__ assign, const float* __restrict__ x,
    float* __restrict__ gacc) {
    __shared__ float csum[264];
    int t = threadIdx.x, lane = t & 63, wid = t >> 6;
    for (int i = t; i < 264; i += 256) csum[i] = 0.f;
    __syncthreads();
    float f0 = 0.f, f1 = 0.f, f2 = 0.f, f3 = 0.f;
    float cnt = 0.f, cf = 0.f;
    int nw = gridDim.x * 4;
    for (int n = blockIdx.x * 4 + wid; n < NN; n += nw) {
        float v = bf2f(xh2b[n * 64 + lane]);
        float4 c4 = *(const float4*)(cs + n * 4);
        f0 = fmaf(c4.x, v, f0);
        f1 = fmaf(c4.y, v, f1);
        f2 = fmaf(c4.z, v, f2);
        f3 = fmaf(c4.w, v, f3);
        if (lane < 4) {
            int a = assign[n];
            if (a == lane) { cnt += 1.f; cf += x[n * 7 + 6]; }
        }
    }
    atomicAdd(&csum[0 * 64 + lane], f0);
    atomicAdd(&csum[1 * 64 + lane], f1);
    atomicAdd(&csum[2 * 64 + lane], f2);
    atomicAdd(&csum[3 * 64 + lane], f3);
    if (lane < 4) {
        atomicAdd(&csum[256 + lane], cnt);
        atomicAdd(&csum[260 + lane], cf);
    }
    __syncthreads();
    for (int i = t; i < 264; i += 256) atomicAdd(&gacc[i], csum[i]);
}

// final head: cluster means (+cnt*b2), actor MLP + softmax, critic MLP
__global__ void k_head(const float* __restrict__ gacc, const float* __restrict__ b2,
                       const float* __restrict__ A1, const float* __restrict__ ba1,
                       const float* __restrict__ A2, const float* __restrict__ ba2,
                       const float* __restrict__ C1, const float* __restrict__ bc1,
                       const float* __restrict__ C2, const float* __restrict__ bc2,
                       float* __restrict__ out) {
    __shared__ float zc[4][64];
    __shared__ float cfs[4];
    __shared__ float logits[4];
    int j = threadIdx.x; // 64
    float b2j = b2[j];
    #pragma unroll
    for (int c = 0; c < 4; ++c) {
        float cnt = gacc[256 + c];
        float den = fmaxf(cnt, 1.f);
        zc[c][j] = (cnt > 0.f) ? (gacc[c * 64 + j] + cnt * b2j) / den : 0.f;
        if (j == 0) cfs[c] = (cnt > 0.f) ? gacc[260 + c] / den : 0.f;
    }
    __syncthreads();
    #pragma unroll
    for (int c = 0; c < 4; ++c) {
        float tv = ba1[j];
        for (int k = 0; k < 64; ++k) tv += zc[c][k] * A1[k * 64 + j];
        tv += cfs[c] * A1[64 * 64 + j];
        tv = fmaxf(tv, 0.f);
        float s = wave_reduce_sum(tv * A2[j]);
        if (j == 0) logits[c] = s + ba2[0];
    }
    float vj = bc1[j];
    for (int k = 0; k < 256; ++k) vj += zc[k >> 6][k & 63] * C1[k * 64 + j];
    vj = fmaxf(vj, 0.f);
    float v = wave_reduce_sum(vj * C2[j]);
    __syncthreads();
    if (j == 0) {
        float m = fmaxf(fmaxf(logits[0], logits[1]), fmaxf(logits[2], logits[3]));
        float e0 = __expf(logits[0] - m), e1 = __expf(logits[1] - m);
        float e2 = __expf(logits[2] - m), e3 = __expf(logits[3] - m);
        float sum = e0 + e1 + e2 + e3;
        out[0] = e0 / sum; out[1] = e1 / sum; out[2] = e2 / sum; out[3] = e3 / sum;
        out[4] = v + bc2[0];
    }
    #pragma unroll
    for (int c = 0; c < 4; ++c) out[5 + c * 64 + j] = zc[c][j];
}

extern "C" void kernel_launch(void* const* d_in, const int* in_sizes, int n_in,
                              void* d_out, int out_size, void* d_ws, size_t ws_size,
                              hipStream_t stream) {
    const float* x    = (const float*)d_in[0];
    const int*   ei   = (const int*)d_in[1];
    const float* ea   = (const float*)d_in[2];
    const int*   asg  = (const int*)d_in[3];
    const float* W1   = (const float*)d_in[4];
    const float* as1  = (const float*)d_in[5];
    const float* ad1  = (const float*)d_in[6];
    const float* We1  = (const float*)d_in[7];
    const float* ae1  = (const float*)d_in[8];
    const float* b1   = (const float*)d_in[9];
    const float* W2   = (const float*)d_in[10];
    const float* as2  = (const float*)d_in[11];
    const float* ad2  = (const float*)d_in[12];
    const float* We2  = (const float*)d_in[13];
    const float* ae2  = (const float*)d_in[14];
    const float* b2   = (const float*)d_in[15];
    const float* A1   = (const float*)d_in[16];
    const float* ba1  = (const float*)d_in[17];
    const float* A2   = (const float*)d_in[18];
    const float* ba2  = (const float*)d_in[19];
    const float* C1   = (const float*)d_in[20];
    const float* bc1  = (const float*)d_in[21];
    const float* C2   = (const float*)d_in[22];
    const float* bc2  = (const float*)d_in[23];
    const int* src = ei;
    const int* dst = ei + NE;

    char* w = (char*)d_ws;
    size_t off = 0;
    auto alloc = [&](size_t bytes) -> void* {
        void* p = w + off;
        off += (bytes + 255) & ~(size_t)255;
        return p;
    };
    // contiguous zero-init region first: hist | z1 | cs | gacc
    int*   hist   = (int*)alloc(NN * sizeof(int));
    float* z1     = (float*)alloc(NN * sizeof(float));
    float* cs     = (float*)alloc(NN * 4 * sizeof(float));
    float* gacc   = (float*)alloc(264 * sizeof(float));
    size_t zspan  = (size_t)((char*)gacc + 264 * sizeof(float) - (char*)hist);
    float* a_src1 = (float*)alloc(NN * 4 * sizeof(float));
    float* a_dst1 = (float*)alloc(NN * 4 * sizeof(float));
    float* a_src2 = (float*)alloc(NN * sizeof(float));
    float* a_dst2 = (float*)alloc(NN * sizeof(float));
    int*   offs   = (int*)alloc((NN + 1) * sizeof(int));
    int*   cursor = (int*)alloc(NN * sizeof(int));
    int*   bsum   = (int*)alloc(128 * sizeof(int));
    int*   bexcl  = (int*)alloc(128 * sizeof(int));
    int2*  es_se  = (int2*)alloc(NE * sizeof(int2));
    float* ew_o   = (float*)alloc(NE * sizeof(float));
    unsigned short* xh2b = (unsigned short*)alloc(NN * 64 * sizeof(unsigned short));
    unsigned short* W2fr = (unsigned short*)alloc(16384 * sizeof(unsigned short));
    float* cb     = (float*)alloc(576 * sizeof(float));
    (void)ws_size; (void)n_in; (void)in_sizes; (void)out_size;

    hipMemsetAsync(hist, 0, zspan, stream);

    k_pre<<<65, 256, 0, stream>>>(W1, as1, ad1, We1, ae1, We2, ae2, W2, as2, ad2, cb, W2fr);
    k_node1<<<(NN + 255) / 256, 256, 0, stream>>>(x, cb, a_src1, a_dst1);
    k_hist<<<(NE / 4 + 255) / 256, 256, 0, stream>>>(dst, hist);
    k_scanA<<<98, 1024, 0, stream>>>(hist, bsum);
    k_scanB<<<1, 128, 0, stream>>>(bsum, bexcl);
    k_scanC<<<98, 1024, 0, stream>>>(hist, bexcl, offs, cursor);
    k_scatter<<<(NE + 255) / 256, 256, 0, stream>>>(src, dst, ea, cursor, es_se);
    k_conv1red<<<NN / 32, 256, 0, stream>>>(x, W1, b1, cb, offs, es_se, a_src1, a_dst1,
                                            W2fr, xh2b, a_src2, a_dst2);
    k_zA<<<(NE + 255) / 256, 256, 0, stream>>>(src, dst, ea, a_src2, a_dst2, cb, ew_o, z1);
    k_zB<<<(NE + 255) / 256, 256, 0, stream>>>(src, dst, ew_o, z1, asg, cs);
    k_pool<<<256, 256, 0, stream>>>(xh2b, cs, asg, x, gacc);
    k_head<<<1, 64, 0, stream>>>(gacc, b2, A1, ba1, A2, ba2, C1, bc1, C2, bc2, (float*)d_out);
}

// Round 7
// 322.224 us; speedup vs baseline: 1.0447x; 1.0124x over previous
//
#include <hip/hip_runtime.h>

#define NN 100000
#define NE 800000
#define NPB 512   // k_pool blocks

typedef short bf16x8 __attribute__((ext_vector_type(8)));
typedef float f32x4 __attribute__((ext_vector_type(4)));

__device__ __forceinline__ float wave_reduce_sum(float v) {
    #pragma unroll
    for (int o = 32; o > 0; o >>= 1) v += __shfl_down(v, o, 64);
    return v; // valid in lane 0
}

__device__ __forceinline__ unsigned short f2bf(float f) {
    unsigned u = __float_as_uint(f);
    unsigned r = (u + 0x7FFFu + ((u >> 16) & 1u)) >> 16;
    return (unsigned short)r;
}
__device__ __forceinline__ float bf2f(unsigned short b) {
    return __uint_as_float(((unsigned)b) << 16);
}

// cb layout (floats): [0..27] vs1(k*4+h)  [28..55] vd1  [56..59] c1[h]  [60] c2
//                     [64..319] was2 = W2@as2   [320..575] wad2 = W2@ad2
__global__ void k_pre(const float* __restrict__ W1, const float* __restrict__ as1,
                      const float* __restrict__ ad1,
                      const float* __restrict__ We1, const float* __restrict__ ae1,
                      const float* __restrict__ We2, const float* __restrict__ ae2,
                      const float* __restrict__ W2, const float* __restrict__ as2,
                      const float* __restrict__ ad2,
                      float* __restrict__ cb, unsigned short* __restrict__ W2fr) {
    int t = threadIdx.x;
    if (blockIdx.x == 0) {
        if (t < 28) {
            int k = t >> 2, h = t & 3;
            float s = 0.f, d = 0.f;
            for (int c = 0; c < 64; ++c) {
                float w = W1[k * 256 + h * 64 + c];
                s += w * as1[h * 64 + c];
                d += w * ad1[h * 64 + c];
            }
            cb[t] = s; cb[28 + t] = d;
        } else if (t < 32) {
            int h = t - 28;
            float s = 0.f;
            for (int c = 0; c < 64; ++c) s += We1[h * 64 + c] * ae1[h * 64 + c];
            cb[56 + h] = s;
        } else if (t == 32) {
            float s = 0.f;
            for (int c = 0; c < 64; ++c) s += We2[c] * ae2[c];
            cb[60] = s;
        }
        float s = 0.f, d = 0.f;
        for (int j = 0; j < 64; ++j) {
            float w = W2[t * 64 + j];
            s += w * as2[j];
            d += w * ad2[j];
        }
        cb[64 + t] = s;
        cb[320 + t] = d;
    } else {
        int o = (blockIdx.x - 1) * 256 + t;        // 0..16383
        int i = o & 7, l = (o >> 3) & 63, ct = (o >> 9) & 3, ks = o >> 11;
        int k = ks * 32 + ((l >> 4) * 8) + i;
        int col = ct * 16 + (l & 15);
        W2fr[o] = f2bf(W2[k * 64 + col]);
    }
}

// per-node conv1 attention coefficients via folded 7x4 tables
__global__ void k_node1(const float* __restrict__ x, const float* __restrict__ cb,
                        float* __restrict__ a_src1, float* __restrict__ a_dst1) {
    int n = blockIdx.x * 256 + threadIdx.x;
    if (n >= NN) return;
    float xv[7];
    #pragma unroll
    for (int k = 0; k < 7; ++k) xv[k] = x[n * 7 + k];
    float s[4] = {0.f, 0.f, 0.f, 0.f}, d[4] = {0.f, 0.f, 0.f, 0.f};
    #pragma unroll
    for (int k = 0; k < 7; ++k)
        #pragma unroll
        for (int h = 0; h < 4; ++h) {
            s[h] += xv[k] * cb[k * 4 + h];
            d[h] += xv[k] * cb[28 + k * 4 + h];
        }
    *(float4*)(a_src1 + n * 4) = make_float4(s[0], s[1], s[2], s[3]);
    *(float4*)(a_dst1 + n * 4) = make_float4(d[0], d[1], d[2], d[3]);
}

__global__ void k_hist(const int* __restrict__ dst, int* __restrict__ hist) {
    int e0 = (blockIdx.x * 256 + threadIdx.x) * 4;
    if (e0 >= NE) return;
    int4 d = *(const int4*)(dst + e0);
    atomicAdd(&hist[d.x], 1);
    atomicAdd(&hist[d.y], 1);
    atomicAdd(&hist[d.z], 1);
    atomicAdd(&hist[d.w], 1);
}

// --- 3-phase parallel exclusive scan over hist[NN] -> offs[NN+1], cursor[NN] ---
__global__ __launch_bounds__(1024) void k_scanA(const int* __restrict__ hist,
                                                int* __restrict__ bsum) {
    __shared__ int ws[16];
    int i = blockIdx.x * 1024 + threadIdx.x;
    int lane = threadIdx.x & 63, wid = threadIdx.x >> 6;
    int v = (i < NN) ? hist[i] : 0;
    #pragma unroll
    for (int o = 32; o; o >>= 1) v += __shfl_down(v, o, 64);
    if (lane == 0) ws[wid] = v;
    __syncthreads();
    if (wid == 0) {
        int u = (lane < 16) ? ws[lane] : 0;
        #pragma unroll
        for (int o = 8; o; o >>= 1) u += __shfl_down(u, o, 64);
        if (lane == 0) bsum[blockIdx.x] = u;
    }
}

__global__ void k_scanB(const int* __restrict__ bsum, int* __restrict__ bexcl) {
    __shared__ int w0tot;
    int t = threadIdx.x, lane = t & 63, wid = t >> 6;
    int v = (t < 98) ? bsum[t] : 0;
    int s = v;
    #pragma unroll
    for (int d = 1; d < 64; d <<= 1) { int u = __shfl_up(s, d, 64); if (lane >= d) s += u; }
    if (t == 63) w0tot = s;
    __syncthreads();
    if (wid == 1) s += w0tot;
    if (t < 98) bexcl[t] = s - v;
}

__global__ __launch_bounds__(1024) void k_scanC(const int* __restrict__ hist,
                                                const int* __restrict__ bexcl,
                                                int* __restrict__ offs,
                                                int* __restrict__ cursor) {
    __shared__ int ws[16];
    int b = blockIdx.x;
    int i = b * 1024 + threadIdx.x;
    int lane = threadIdx.x & 63, wid = threadIdx.x >> 6;
    int v = (i < NN) ? hist[i] : 0;
    int s = v;
    #pragma unroll
    for (int d = 1; d < 64; d <<= 1) { int u = __shfl_up(s, d, 64); if (lane >= d) s += u; }
    if (lane == 63) ws[wid] = s;
    __syncthreads();
    if (wid == 0) {
        int u2 = (lane < 16) ? ws[lane] : 0;
        #pragma unroll
        for (int d = 1; d < 16; d <<= 1) { int uu = __shfl_up(u2, d, 64); if (lane >= d) u2 += uu; }
        if (lane < 16) ws[lane] = u2;
    }
    __syncthreads();
    int incl = s + (wid ? ws[wid - 1] : 0) + bexcl[b];
    if (i < NN) { offs[i + 1] = incl; cursor[i] = incl - v; }
    if (i == 0) offs[0] = 0;
}

// minimal scatter (x4 batched): sorted position + packed (src, ea)
__global__ void k_scatter(const int* __restrict__ src, const int* __restrict__ dst,
                          const float* __restrict__ ea,
                          int* __restrict__ cursor, int2* __restrict__ es_se) {
    int e0 = (blockIdx.x * 256 + threadIdx.x) * 4;
    if (e0 >= NE) return;
    int4 s4 = *(const int4*)(src + e0);
    int4 d4 = *(const int4*)(dst + e0);
    float4 a4 = *(const float4*)(ea + e0);
    int p0 = atomicAdd(&cursor[d4.x], 1);
    int p1 = atomicAdd(&cursor[d4.y], 1);
    int p2 = atomicAdd(&cursor[d4.z], 1);
    int p3 = atomicAdd(&cursor[d4.w], 1);
    es_se[p0] = make_int2(s4.x, __float_as_int(a4.x));
    es_se[p1] = make_int2(s4.y, __float_as_int(a4.y));
    es_se[p2] = make_int2(s4.z, __float_as_int(a4.z));
    es_se[p3] = make_int2(s4.w, __float_as_int(a4.w));
}

// fused conv1: two-phase LDS-staged segmented reduce -> h -> a_src2/a_dst2 -> MFMA -> xh2 bf16
__global__ __launch_bounds__(256) void k_conv1red(
    const float* __restrict__ x, const float* __restrict__ W1, const float* __restrict__ b1,
    const float* __restrict__ cb, const int* __restrict__ offs,
    const int2* __restrict__ es_se,
    const float* __restrict__ a_src1, const float* __restrict__ a_dst1,
    const unsigned short* __restrict__ W2fr,
    unsigned short* __restrict__ xh2b, float* __restrict__ a_src2, float* __restrict__ a_dst2) {
    __shared__ int soffs[33];
    __shared__ float4 ad1L[32];
    __shared__ float xw[256][13];
    __shared__ float ms[32][33];
    __shared__ __attribute__((aligned(16))) unsigned short hs[32][264];
    int t = threadIdx.x, lane = t & 63, wid = t >> 6;
    int n0 = blockIdx.x * 32;
    if (t <= 32) soffs[t] = offs[n0 + t];
    if (t < 32) ad1L[t] = *(const float4*)(a_dst1 + (n0 + t) * 4);
    float w1r[7][4], b1r[4], was2r[4], wad2r[4];
    #pragma unroll
    for (int k = 0; k < 7; ++k)
        #pragma unroll
        for (int h = 0; h < 4; ++h) w1r[k][h] = W1[k * 256 + h * 64 + lane];
    #pragma unroll
    for (int h = 0; h < 4; ++h) {
        b1r[h] = b1[h * 64 + lane];
        was2r[h] = cb[64 + h * 64 + lane];
        wad2r[h] = cb[320 + h * 64 + lane];
    }
    float c56 = cb[56], c57 = cb[57], c58 = cb[58], c59 = cb[59];
    __syncthreads();
    int E0 = soffs[0], E1 = soffs[32];
    int g = t >> 3, q = t & 7;
    int go0 = soffs[g], go1 = soffs[g + 1];
    float mh0 = 0.f, mh1 = 0.f, mh2 = 0.f, mh3 = 0.f;
    for (int C0 = E0; C0 < E1; C0 += 256) {
        int C1 = min(C0 + 256, E1);
        int j = C0 + t;
        if (j < C1) {
            int2 se = es_se[j];
            int s = se.x;
            float eav = __int_as_float(se.y);
            int g2 = 0;
            #pragma unroll
            for (int st = 16; st; st >>= 1)
                if (soffs[g2 + st] <= j) g2 += st;
            float4 as_ = *(const float4*)(a_src1 + s * 4);
            float4 ad_ = ad1L[g2];
            float lg0 = as_.x + ad_.x + eav * c56;
            float lg1 = as_.y + ad_.y + eav * c57;
            float lg2 = as_.z + ad_.z + eav * c58;
            float lg3 = as_.w + ad_.w + eav * c59;
            lg0 = lg0 >= 0.f ? lg0 : 0.2f * lg0;
            lg1 = lg1 >= 0.f ? lg1 : 0.2f * lg1;
            lg2 = lg2 >= 0.f ? lg2 : 0.2f * lg2;
            lg3 = lg3 >= 0.f ? lg3 : 0.2f * lg3;
            const float* xp = x + s * 7;
            xw[t][0] = xp[0]; xw[t][1] = xp[1]; xw[t][2] = xp[2]; xw[t][3] = xp[3];
            xw[t][4] = xp[4]; xw[t][5] = xp[5]; xw[t][6] = xp[6]; xw[t][7] = 1.f;
            xw[t][8] = __expf(lg0); xw[t][9] = __expf(lg1);
            xw[t][10] = __expf(lg2); xw[t][11] = __expf(lg3);
        }
        __syncthreads();
        int lo = max(go0, C0) - C0, hi = min(go1, C1) - C0;
        for (int jj = lo; jj < hi; ++jj) {
            float xv = xw[jj][q];
            mh0 = fmaf(xw[jj][8], xv, mh0);
            mh1 = fmaf(xw[jj][9], xv, mh1);
            mh2 = fmaf(xw[jj][10], xv, mh2);
            mh3 = fmaf(xw[jj][11], xv, mh3);
        }
        __syncthreads();
    }
    ms[g][0 * 8 + q] = mh0; ms[g][1 * 8 + q] = mh1;
    ms[g][2 * 8 + q] = mh2; ms[g][3 * 8 + q] = mh3;
    __syncthreads();
    for (int gi = wid * 8; gi < wid * 8 + 8; ++gi) {
        int n = n0 + gi;
        bool has = soffs[gi + 1] > soffs[gi];
        float ps = 0.f, pd = 0.f;
        #pragma unroll
        for (int h = 0; h < 4; ++h) {
            float z = ms[gi][h * 8 + 7];
            float a = 0.f;
            #pragma unroll
            for (int k = 0; k < 7; ++k) a = fmaf(ms[gi][h * 8 + k], w1r[k][h], a);
            float mm = (has ? a / z : 0.f) + b1r[h];
            float hv = mm > 0.f ? mm : (__expf(mm) - 1.f);
            ps += hv * was2r[h];
            pd += hv * wad2r[h];
            hs[gi][h * 64 + lane] = f2bf(hv);
        }
        ps = wave_reduce_sum(ps);
        pd = wave_reduce_sum(pd);
        if (lane == 0) { a_src2[n] = ps; a_dst2[n] = pd; }
    }
    __syncthreads();
    int row = lane & 15, kg = lane >> 4;
    #pragma unroll
    for (int u = wid; u < 8; u += 4) {
        int nt = u & 1, ct = u >> 1;
        f32x4 acc = {0.f, 0.f, 0.f, 0.f};
        #pragma unroll
        for (int ks = 0; ks < 8; ++ks) {
            bf16x8 av = *(const bf16x8*)&hs[nt * 16 + row][ks * 32 + kg * 8];
            bf16x8 bv = *(const bf16x8*)(W2fr + (((ks * 4 + ct) * 64) + lane) * 8);
            acc = __builtin_amdgcn_mfma_f32_16x16x32_bf16(av, bv, acc, 0, 0, 0);
        }
        #pragma unroll
        for (int i = 0; i < 4; ++i)
            xh2b[(n0 + nt * 16 + kg * 4 + i) * 64 + ct * 16 + row] = f2bf(acc[i]);
    }
}

// conv2 pass A (x4 batched): ew = exp(leaky(logit)), z1[dst] += ew
__global__ void k_zA(const int* __restrict__ src, const int* __restrict__ dst,
                     const float* __restrict__ ea,
                     const float* __restrict__ a_src2, const float* __restrict__ a_dst2,
                     const float* __restrict__ cb,
                     float* __restrict__ ew_o, float* __restrict__ z1) {
    int e0 = (blockIdx.x * 256 + threadIdx.x) * 4;
    if (e0 >= NE) return;
    int4 s4 = *(const int4*)(src + e0);
    int4 d4 = *(const int4*)(dst + e0);
    float4 a4 = *(const float4*)(ea + e0);
    float c2 = cb[60];
    float l0 = a_src2[s4.x] + a_dst2[d4.x] + a4.x * c2;
    float l1 = a_src2[s4.y] + a_dst2[d4.y] + a4.y * c2;
    float l2 = a_src2[s4.z] + a_dst2[d4.z] + a4.z * c2;
    float l3 = a_src2[s4.w] + a_dst2[d4.w] + a4.w * c2;
    l0 = l0 >= 0.f ? l0 : 0.2f * l0;
    l1 = l1 >= 0.f ? l1 : 0.2f * l1;
    l2 = l2 >= 0.f ? l2 : 0.2f * l2;
    l3 = l3 >= 0.f ? l3 : 0.2f * l3;
    float w0 = __expf(l0), w1 = __expf(l1), w2 = __expf(l2), w3 = __expf(l3);
    *(float4*)(ew_o + e0) = make_float4(w0, w1, w2, w3);
    atomicAdd(&z1[d4.x], w0);
    atomicAdd(&z1[d4.y], w1);
    atomicAdd(&z1[d4.z], w2);
    atomicAdd(&z1[d4.w], w3);
}

// conv2 pass B (x4 batched): cs[src][cluster(dst)] += ew / z1[dst]
__global__ void k_zB(const int* __restrict__ src, const int* __restrict__ dst,
                     const float* __restrict__ ew_o, const float* __restrict__ z1,
                     const int* __restrict__ assign, float* __restrict__ cs) {
    int e0 = (blockIdx.x * 256 + threadIdx.x) * 4;
    if (e0 >= NE) return;
    int4 s4 = *(const int4*)(src + e0);
    int4 d4 = *(const int4*)(dst + e0);
    float4 w4 = *(const float4*)(ew_o + e0);
    float z0 = z1[d4.x], zz1 = z1[d4.y], z2 = z1[d4.z], z3 = z1[d4.w];
    int c0 = assign[d4.x], c1 = assign[d4.y], c2 = assign[d4.z], c3 = assign[d4.w];
    atomicAdd(&cs[s4.x * 4 + c0], w4.x / z0);
    atomicAdd(&cs[s4.y * 4 + c1], w4.y / zz1);
    atomicAdd(&cs[s4.z * 4 + c2], w4.z / z2);
    atomicAdd(&cs[s4.w * 4 + c3], w4.w / z3);
}

// pooling as tiny GEMM: partial[i][b] over 512 blocks; 8 lanes/node, 16B loads
__global__ __launch_bounds__(256) void k_pool(
    const unsigned short* __restrict__ xh2b, const float* __restrict__ cs,
    const int* __restrict__ assign, const float* __restrict__ x,
    float* __restrict__ partial) {
    __shared__ float csum[264];
    int t = threadIdx.x;
    int q = t & 7, slot = t >> 3;             // 32 node-slots per block
    float a0[8], a1[8], a2[8], a3[8];
    #pragma unroll
    for (int j = 0; j < 8; ++j) { a0[j] = 0.f; a1[j] = 0.f; a2[j] = 0.f; a3[j] = 0.f; }
    float cnt0 = 0.f, cnt1 = 0.f, cnt2 = 0.f, cnt3 = 0.f;
    float cf0 = 0.f, cf1 = 0.f, cf2 = 0.f, cf3 = 0.f;
    for (int n = blockIdx.x * 32 + slot; n < NN; n += NPB * 32) {
        uint4 u = *(const uint4*)(xh2b + n * 64 + q * 8);
        float4 c4 = *(const float4*)(cs + n * 4);
        float xv[8];
        xv[0] = bf2f((unsigned short)u.x); xv[1] = bf2f((unsigned short)(u.x >> 16));
        xv[2] = bf2f((unsigned short)u.y); xv[3] = bf2f((unsigned short)(u.y >> 16));
        xv[4] = bf2f((unsigned short)u.z); xv[5] = bf2f((unsigned short)(u.z >> 16));
        xv[6] = bf2f((unsigned short)u.w); xv[7] = bf2f((unsigned short)(u.w >> 16));
        #pragma unroll
        for (int j = 0; j < 8; ++j) {
            a0[j] = fmaf(c4.x, xv[j], a0[j]);
            a1[j] = fmaf(c4.y, xv[j], a1[j]);
            a2[j] = fmaf(c4.z, xv[j], a2[j]);
            a3[j] = fmaf(c4.w, xv[j], a3[j]);
        }
        if (q == 0) {
            int a = assign[n];
            float xf = x[n * 7 + 6];
            cnt0 += (a == 0) ? 1.f : 0.f;  cf0 += (a == 0) ? xf : 0.f;
            cnt1 += (a == 1) ? 1.f : 0.f;  cf1 += (a == 1) ? xf : 0.f;
            cnt2 += (a == 2) ? 1.f : 0.f;  cf2 += (a == 2) ? xf : 0.f;
            cnt3 += (a == 3) ? 1.f : 0.f;  cf3 += (a == 3) ? xf : 0.f;
        }
    }
    for (int i = t; i < 264; i += 256) csum[i] = 0.f;
    __syncthreads();
    int base = q * 8;
    #pragma unroll
    for (int j = 0; j < 8; ++j) {
        atomicAdd(&csum[0 * 64 + base + j], a0[j]);
        atomicAdd(&csum[1 * 64 + base + j], a1[j]);
        atomicAdd(&csum[2 * 64 + base + j], a2[j]);
        atomicAdd(&csum[3 * 64 + base + j], a3[j]);
    }
    if (q == 0) {
        atomicAdd(&csum[256], cnt0); atomicAdd(&csum[257], cnt1);
        atomicAdd(&csum[258], cnt2); atomicAdd(&csum[259], cnt3);
        atomicAdd(&csum[260], cf0);  atomicAdd(&csum[261], cf1);
        atomicAdd(&csum[262], cf2);  atomicAdd(&csum[263], cf3);
    }
    __syncthreads();
    for (int i = t; i < 264; i += 256) partial[i * NPB + blockIdx.x] = csum[i];
}

// reduce partials -> gacc[264]
__global__ __launch_bounds__(512) void k_pool2(const float* __restrict__ partial,
                                               float* __restrict__ gacc) {
    int i = threadIdx.x;
    if (i >= 264) return;
    const float* p = partial + i * NPB;
    float s = 0.f;
    #pragma unroll 4
    for (int b = 0; b < NPB; b += 4) {
        float4 v = *(const float4*)(p + b);
        s += v.x + v.y + v.z + v.w;
    }
    gacc[i] = s;
}

// final head: cluster means (+cnt*b2), actor MLP + softmax, critic MLP
__global__ void k_head(const float* __restrict__ gacc, const float* __restrict__ b2,
                       const float* __restrict__ A1, const float* __restrict__ ba1,
                       const float* __restrict__ A2, const float* __restrict__ ba2,
                       const float* __restrict__ C1, const float* __restrict__ bc1,
                       const float* __restrict__ C2, const float* __restrict__ bc2,
                       float* __restrict__ out) {
    __shared__ float zc[4][64];
    __shared__ float cfs[4];
    __shared__ float logits[4];
    int j = threadIdx.x; // 64
    float b2j = b2[j];
    #pragma unroll
    for (int c = 0; c < 4; ++c) {
        float cnt = gacc[256 + c];
        float den = fmaxf(cnt, 1.f);
        zc[c][j] = (cnt > 0.f) ? (gacc[c * 64 + j] + cnt * b2j) / den : 0.f;
        if (j == 0) cfs[c] = (cnt > 0.f) ? gacc[260 + c] / den : 0.f;
    }
    __syncthreads();
    #pragma unroll
    for (int c = 0; c < 4; ++c) {
        float tv = ba1[j];
        for (int k = 0; k < 64; ++k) tv += zc[c][k] * A1[k * 64 + j];
        tv += cfs[c] * A1[64 * 64 + j];
        tv = fmaxf(tv, 0.f);
        float s = wave_reduce_sum(tv * A2[j]);
        if (j == 0) logits[c] = s + ba2[0];
    }
    float vj = bc1[j];
    for (int k = 0; k < 256; ++k) vj += zc[k >> 6][k & 63] * C1[k * 64 + j];
    vj = fmaxf(vj, 0.f);
    float v = wave_reduce_sum(vj * C2[j]);
    __syncthreads();
    if (j == 0) {
        float m = fmaxf(fmaxf(logits[0], logits[1]), fmaxf(logits[2], logits[3]));
        float e0 = __expf(logits[0] - m), e1 = __expf(logits[1] - m);
        float e2 = __expf(logits[2] - m), e3 = __expf(logits[3] - m);
        float sum = e0 + e1 + e2 + e3;
        out[0] = e0 / sum; out[1] = e1 / sum; out[2] = e2 / sum; out[3] = e3 / sum;
        out[4] = v + bc2[0];
    }
    #pragma unroll
    for (int c = 0; c < 4; ++c) out[5 + c * 64 + j] = zc[c][j];
}

extern "C" void kernel_launch(void* const* d_in, const int* in_sizes, int n_in,
                              void* d_out, int out_size, void* d_ws, size_t ws_size,
                              hipStream_t stream) {
    const float* x    = (const float*)d_in[0];
    const int*   ei   = (const int*)d_in[1];
    const float* ea   = (const float*)d_in[2];
    const int*   asg  = (const int*)d_in[3];
    const float* W1   = (const float*)d_in[4];
    const float* as1  = (const float*)d_in[5];
    const float* ad1  = (const float*)d_in[6];
    const float* We1  = (const float*)d_in[7];
    const float* ae1  = (const float*)d_in[8];
    const float* b1   = (const float*)d_in[9];
    const float* W2   = (const float*)d_in[10];
    const float* as2  = (const float*)d_in[11];
    const float* ad2  = (const float*)d_in[12];
    const float* We2  = (const float*)d_in[13];
    const float* ae2  = (const float*)d_in[14];
    const float* b2   = (const float*)d_in[15];
    const float* A1   = (const float*)d_in[16];
    const float* ba1  = (const float*)d_in[17];
    const float* A2   = (const float*)d_in[18];
    const float* ba2  = (const float*)d_in[19];
    const float* C1   = (const float*)d_in[20];
    const float* bc1  = (const float*)d_in[21];
    const float* C2   = (const float*)d_in[22];
    const float* bc2  = (const float*)d_in[23];
    const int* src = ei;
    const int* dst = ei + NE;

    char* w = (char*)d_ws;
    size_t off = 0;
    auto alloc = [&](size_t bytes) -> void* {
        void* p = w + off;
        off += (bytes + 255) & ~(size_t)255;
        return p;
    };
    // contiguous zero-init region: hist | z1 | cs
    int*   hist   = (int*)alloc(NN * sizeof(int));
    float* z1     = (float*)alloc(NN * sizeof(float));
    float* cs     = (float*)alloc(NN * 4 * sizeof(float));
    size_t zspan  = (size_t)((char*)cs + NN * 4 * sizeof(float) - (char*)hist);
    float* gacc   = (float*)alloc(264 * sizeof(float));
    float* partial= (float*)alloc(264 * NPB * sizeof(float));
    float* a_src1 = (float*)alloc(NN * 4 * sizeof(float));
    float* a_dst1 = (float*)alloc(NN * 4 * sizeof(float));
    float* a_src2 = (float*)alloc(NN * sizeof(float));
    float* a_dst2 = (float*)alloc(NN * sizeof(float));
    int*   offs   = (int*)alloc((NN + 1) * sizeof(int));
    int*   cursor = (int*)alloc(NN * sizeof(int));
    int*   bsum   = (int*)alloc(128 * sizeof(int));
    int*   bexcl  = (int*)alloc(128 * sizeof(int));
    int2*  es_se  = (int2*)alloc(NE * sizeof(int2));
    float* ew_o   = (float*)alloc(NE * sizeof(float));
    unsigned short* xh2b = (unsigned short*)alloc(NN * 64 * sizeof(unsigned short));
    unsigned short* W2fr = (unsigned short*)alloc(16384 * sizeof(unsigned short));
    float* cb     = (float*)alloc(576 * sizeof(float));
    (void)ws_size; (void)n_in; (void)in_sizes; (void)out_size;

    hipMemsetAsync(hist, 0, zspan, stream);

    k_pre<<<65, 256, 0, stream>>>(W1, as1, ad1, We1, ae1, We2, ae2, W2, as2, ad2, cb, W2fr);
    k_node1<<<(NN + 255) / 256, 256, 0, stream>>>(x, cb, a_src1, a_dst1);
    k_hist<<<(NE / 4 + 255) / 256, 256, 0, stream>>>(dst, hist);
    k_scanA<<<98, 1024, 0, stream>>>(hist, bsum);
    k_scanB<<<1, 128, 0, stream>>>(bsum, bexcl);
    k_scanC<<<98, 1024, 0, stream>>>(hist, bexcl, offs, cursor);
    k_scatter<<<(NE / 4 + 255) / 256, 256, 0, stream>>>(src, dst, ea, cursor, es_se);
    k_conv1red<<<NN / 32, 256, 0, stream>>>(x, W1, b1, cb, offs, es_se, a_src1, a_dst1,
                                            W2fr, xh2b, a_src2, a_dst2);
    k_zA<<<(NE / 4 + 255) / 256, 256, 0, stream>>>(src, dst, ea, a_src2, a_dst2, cb, ew_o, z1);
    k_zB<<<(NE / 4 + 255) / 256, 256, 0, stream>>>(src, dst, ew_o, z1, asg, cs);
    k_pool<<<NPB, 256, 0, stream>>>(xh2b, cs, asg, x, partial);
    k_pool2<<<1, 512, 0, stream>>>(partial, gacc);
    k_head<<<1, 64, 0, stream>>>(gacc, b2, A1, ba1, A2, ba2, C1, bc1, C2, bc2, (float*)d_out);
}

// Round 8
// 245.189 us; speedup vs baseline: 1.3729x; 1.3142x over previous
//
#include <hip/hip_runtime.h>

#define NN 100000
#define NE 800000
#define NPB 512   // k_pool blocks

typedef short bf16x8 __attribute__((ext_vector_type(8)));
typedef float f32x4 __attribute__((ext_vector_type(4)));

__device__ __forceinline__ float wave_reduce_sum(float v) {
    #pragma unroll
    for (int o = 32; o > 0; o >>= 1) v += __shfl_down(v, o, 64);
    return v; // valid in lane 0
}

__device__ __forceinline__ unsigned short f2bf(float f) {
    unsigned u = __float_as_uint(f);
    unsigned r = (u + 0x7FFFu + ((u >> 16) & 1u)) >> 16;
    return (unsigned short)r;
}
__device__ __forceinline__ float bf2f(unsigned short b) {
    return __uint_as_float(((unsigned)b) << 16);
}

// cb layout (floats): [0..27] vs1(k*4+h)  [28..55] vd1  [56..59] c1[h]  [60] c2
__global__ void k_pre(const float* __restrict__ W1, const float* __restrict__ as1,
                      const float* __restrict__ ad1,
                      const float* __restrict__ We1, const float* __restrict__ ae1,
                      const float* __restrict__ We2, const float* __restrict__ ae2,
                      const float* __restrict__ W2,
                      float* __restrict__ cb, unsigned short* __restrict__ W2fr) {
    int t = threadIdx.x;
    if (blockIdx.x == 0) {
        if (t < 28) {
            int k = t >> 2, h = t & 3;
            float s = 0.f, d = 0.f;
            for (int c = 0; c < 64; ++c) {
                float w = W1[k * 256 + h * 64 + c];
                s += w * as1[h * 64 + c];
                d += w * ad1[h * 64 + c];
            }
            cb[t] = s; cb[28 + t] = d;
        } else if (t < 32) {
            int h = t - 28;
            float s = 0.f;
            for (int c = 0; c < 64; ++c) s += We1[h * 64 + c] * ae1[h * 64 + c];
            cb[56 + h] = s;
        } else if (t == 32) {
            float s = 0.f;
            for (int c = 0; c < 64; ++c) s += We2[c] * ae2[c];
            cb[60] = s;
        }
    } else {
        int o = (blockIdx.x - 1) * 256 + t;        // 0..16383
        int i = o & 7, l = (o >> 3) & 63, ct = (o >> 9) & 3, ks = o >> 11;
        int k = ks * 32 + ((l >> 4) * 8) + i;
        int col = ct * 16 + (l & 15);
        W2fr[o] = f2bf(W2[k * 64 + col]);
    }
}

// per-node: conv1 attention coefficients + padded x8 row; fused dst histogram (8 edges/thread)
__global__ void k_node1h(const float* __restrict__ x, const float* __restrict__ cb,
                         const int* __restrict__ dst,
                         float* __restrict__ a_src1, float* __restrict__ a_dst1,
                         float* __restrict__ x8g, int* __restrict__ hist) {
    int n = blockIdx.x * 256 + threadIdx.x;
    if (n >= NN) return;
    float xv[7];
    #pragma unroll
    for (int k = 0; k < 7; ++k) xv[k] = x[n * 7 + k];
    float s[4] = {0.f, 0.f, 0.f, 0.f}, d[4] = {0.f, 0.f, 0.f, 0.f};
    #pragma unroll
    for (int k = 0; k < 7; ++k)
        #pragma unroll
        for (int h = 0; h < 4; ++h) {
            s[h] += xv[k] * cb[k * 4 + h];
            d[h] += xv[k] * cb[28 + k * 4 + h];
        }
    *(float4*)(a_src1 + n * 4) = make_float4(s[0], s[1], s[2], s[3]);
    *(float4*)(a_dst1 + n * 4) = make_float4(d[0], d[1], d[2], d[3]);
    *(float4*)(x8g + n * 8) = make_float4(xv[0], xv[1], xv[2], xv[3]);
    *(float4*)(x8g + n * 8 + 4) = make_float4(xv[4], xv[5], xv[6], 1.f);
    // histogram: edges [n*8, n*8+8)
    int e0 = n * 8;
    int4 d0 = *(const int4*)(dst + e0);
    int4 d1 = *(const int4*)(dst + e0 + 4);
    atomicAdd(&hist[d0.x], 1); atomicAdd(&hist[d0.y], 1);
    atomicAdd(&hist[d0.z], 1); atomicAdd(&hist[d0.w], 1);
    atomicAdd(&hist[d1.x], 1); atomicAdd(&hist[d1.y], 1);
    atomicAdd(&hist[d1.z], 1); atomicAdd(&hist[d1.w], 1);
}

// --- 3-phase parallel exclusive scan over hist[NN] -> offs[NN+1], cursor[NN] ---
__global__ __launch_bounds__(1024) void k_scanA(const int* __restrict__ hist,
                                                int* __restrict__ bsum) {
    __shared__ int ws[16];
    int i = blockIdx.x * 1024 + threadIdx.x;
    int lane = threadIdx.x & 63, wid = threadIdx.x >> 6;
    int v = (i < NN) ? hist[i] : 0;
    #pragma unroll
    for (int o = 32; o; o >>= 1) v += __shfl_down(v, o, 64);
    if (lane == 0) ws[wid] = v;
    __syncthreads();
    if (wid == 0) {
        int u = (lane < 16) ? ws[lane] : 0;
        #pragma unroll
        for (int o = 8; o; o >>= 1) u += __shfl_down(u, o, 64);
        if (lane == 0) bsum[blockIdx.x] = u;
    }
}

__global__ void k_scanB(const int* __restrict__ bsum, int* __restrict__ bexcl) {
    __shared__ int w0tot;
    int t = threadIdx.x, lane = t & 63, wid = t >> 6;
    int v = (t < 98) ? bsum[t] : 0;
    int s = v;
    #pragma unroll
    for (int d = 1; d < 64; d <<= 1) { int u = __shfl_up(s, d, 64); if (lane >= d) s += u; }
    if (t == 63) w0tot = s;
    __syncthreads();
    if (wid == 1) s += w0tot;
    if (t < 98) bexcl[t] = s - v;
}

__global__ __launch_bounds__(1024) void k_scanC(const int* __restrict__ hist,
                                                const int* __restrict__ bexcl,
                                                int* __restrict__ offs,
                                                int* __restrict__ cursor) {
    __shared__ int ws[16];
    int b = blockIdx.x;
    int i = b * 1024 + threadIdx.x;
    int lane = threadIdx.x & 63, wid = threadIdx.x >> 6;
    int v = (i < NN) ? hist[i] : 0;
    int s = v;
    #pragma unroll
    for (int d = 1; d < 64; d <<= 1) { int u = __shfl_up(s, d, 64); if (lane >= d) s += u; }
    if (lane == 63) ws[wid] = s;
    __syncthreads();
    if (wid == 0) {
        int u2 = (lane < 16) ? ws[lane] : 0;
        #pragma unroll
        for (int d = 1; d < 16; d <<= 1) { int uu = __shfl_up(u2, d, 64); if (lane >= d) u2 += uu; }
        if (lane < 16) ws[lane] = u2;
    }
    __syncthreads();
    int incl = s + (wid ? ws[wid - 1] : 0) + bexcl[b];
    if (i < NN) { offs[i + 1] = incl; cursor[i] = incl - v; }
    if (i == 0) offs[0] = 0;
}

// minimal scatter: sorted position + packed (src, ea) — 1 edge/thread for max TLP
__global__ void k_scatter(const int* __restrict__ src, const int* __restrict__ dst,
                          const float* __restrict__ ea,
                          int* __restrict__ cursor, int2* __restrict__ es_se) {
    int e = blockIdx.x * 256 + threadIdx.x;
    if (e >= NE) return;
    int d = dst[e];
    int pos = atomicAdd(&cursor[d], 1);
    es_se[pos] = make_int2(src[e], __float_as_int(ea[e]));
}

// fused conv1: two-phase LDS-staged segmented reduce -> h -> MFMA (xh2 + a_src2/a_dst2 epilogue)
__global__ __launch_bounds__(256) void k_conv1red(
    const float* __restrict__ x8g, const float* __restrict__ W1, const float* __restrict__ b1,
    const float* __restrict__ cb, const int* __restrict__ offs,
    const int2* __restrict__ es_se,
    const float* __restrict__ a_src1, const float* __restrict__ a_dst1,
    const float* __restrict__ as2, const float* __restrict__ ad2,
    const unsigned short* __restrict__ W2fr,
    unsigned short* __restrict__ xh2b, float* __restrict__ a_src2, float* __restrict__ a_dst2) {
    __shared__ int soffs[33];
    __shared__ float4 ad1L[32];
    __shared__ float sacc[32], dacc[32];
    __shared__ float xw[256][13];
    __shared__ float ms[32][33];
    __shared__ __attribute__((aligned(16))) unsigned short hs[32][264];
    int t = threadIdx.x, lane = t & 63, wid = t >> 6;
    int n0 = blockIdx.x * 32;
    if (t <= 32) soffs[t] = offs[n0 + t];
    if (t < 32) {
        ad1L[t] = *(const float4*)(a_dst1 + (n0 + t) * 4);
        sacc[t] = 0.f; dacc[t] = 0.f;
    }
    float w1r[7][4], b1r[4];
    #pragma unroll
    for (int k = 0; k < 7; ++k)
        #pragma unroll
        for (int h = 0; h < 4; ++h) w1r[k][h] = W1[k * 256 + h * 64 + lane];
    #pragma unroll
    for (int h = 0; h < 4; ++h) b1r[h] = b1[h * 64 + lane];
    float c56 = cb[56], c57 = cb[57], c58 = cb[58], c59 = cb[59];
    __syncthreads();
    int E0 = soffs[0], E1 = soffs[32];
    int g = t >> 3, q = t & 7;
    int go0 = soffs[g], go1 = soffs[g + 1];
    float mh0 = 0.f, mh1 = 0.f, mh2 = 0.f, mh3 = 0.f;
    for (int C0 = E0; C0 < E1; C0 += 256) {
        int C1 = min(C0 + 256, E1);
        int j = C0 + t;
        if (j < C1) {
            int2 se = es_se[j];
            int s = se.x;
            float eav = __int_as_float(se.y);
            int g2 = 0;
            #pragma unroll
            for (int st = 16; st; st >>= 1)
                if (soffs[g2 + st] <= j) g2 += st;
            float4 as_ = *(const float4*)(a_src1 + s * 4);
            float4 xa = *(const float4*)(x8g + s * 8);
            float4 xb = *(const float4*)(x8g + s * 8 + 4);
            float4 ad_ = ad1L[g2];
            float lg0 = as_.x + ad_.x + eav * c56;
            float lg1 = as_.y + ad_.y + eav * c57;
            float lg2 = as_.z + ad_.z + eav * c58;
            float lg3 = as_.w + ad_.w + eav * c59;
            lg0 = lg0 >= 0.f ? lg0 : 0.2f * lg0;
            lg1 = lg1 >= 0.f ? lg1 : 0.2f * lg1;
            lg2 = lg2 >= 0.f ? lg2 : 0.2f * lg2;
            lg3 = lg3 >= 0.f ? lg3 : 0.2f * lg3;
            xw[t][0] = xa.x; xw[t][1] = xa.y; xw[t][2] = xa.z; xw[t][3] = xa.w;
            xw[t][4] = xb.x; xw[t][5] = xb.y; xw[t][6] = xb.z; xw[t][7] = 1.f;
            xw[t][8] = __expf(lg0); xw[t][9] = __expf(lg1);
            xw[t][10] = __expf(lg2); xw[t][11] = __expf(lg3);
        }
        __syncthreads();
        int lo = max(go0, C0) - C0, hi = min(go1, C1) - C0;
        for (int jj = lo; jj < hi; ++jj) {
            float xv = xw[jj][q];
            mh0 = fmaf(xw[jj][8], xv, mh0);
            mh1 = fmaf(xw[jj][9], xv, mh1);
            mh2 = fmaf(xw[jj][10], xv, mh2);
            mh3 = fmaf(xw[jj][11], xv, mh3);
        }
        __syncthreads();
    }
    ms[g][0 * 8 + q] = mh0; ms[g][1 * 8 + q] = mh1;
    ms[g][2 * 8 + q] = mh2; ms[g][3 * 8 + q] = mh3;
    __syncthreads();
    // finish: 8 nodes per wave, lane = channel; no cross-lane reductions here
    for (int gi = wid * 8; gi < wid * 8 + 8; ++gi) {
        bool has = soffs[gi + 1] > soffs[gi];
        #pragma unroll
        for (int h = 0; h < 4; ++h) {
            float z = ms[gi][h * 8 + 7];
            float a = 0.f;
            #pragma unroll
            for (int k = 0; k < 7; ++k) a = fmaf(ms[gi][h * 8 + k], w1r[k][h], a);
            float mm = (has ? a / z : 0.f) + b1r[h];
            float hv = mm > 0.f ? mm : (__expf(mm) - 1.f);
            hs[gi][h * 64 + lane] = f2bf(hv);
        }
    }
    __syncthreads();
    // MFMA: 2 node-tiles x 4 col-tiles; epilogue computes a_src2/a_dst2 from acc
    int row = lane & 15, kg = lane >> 4;
    #pragma unroll
    for (int u = wid; u < 8; u += 4) {
        int nt = u & 1, ct = u >> 1;
        f32x4 acc = {0.f, 0.f, 0.f, 0.f};
        #pragma unroll
        for (int ks = 0; ks < 8; ++ks) {
            bf16x8 av = *(const bf16x8*)&hs[nt * 16 + row][ks * 32 + kg * 8];
            bf16x8 bv = *(const bf16x8*)(W2fr + (((ks * 4 + ct) * 64) + lane) * 8);
            acc = __builtin_amdgcn_mfma_f32_16x16x32_bf16(av, bv, acc, 0, 0, 0);
        }
        float as2v = as2[ct * 16 + row];
        float ad2v = ad2[ct * 16 + row];
        #pragma unroll
        for (int i = 0; i < 4; ++i) {
            xh2b[(n0 + nt * 16 + kg * 4 + i) * 64 + ct * 16 + row] = f2bf(acc[i]);
            float ps = acc[i] * as2v;
            float pd = acc[i] * ad2v;
            #pragma unroll
            for (int o = 1; o < 16; o <<= 1) {
                ps += __shfl_xor(ps, o, 64);
                pd += __shfl_xor(pd, o, 64);
            }
            if (row == 0) {
                atomicAdd(&sacc[nt * 16 + kg * 4 + i], ps);
                atomicAdd(&dacc[nt * 16 + kg * 4 + i], pd);
            }
        }
    }
    __syncthreads();
    if (t < 32) {
        a_src2[n0 + t] = sacc[t];
        a_dst2[n0 + t] = dacc[t];
    }
}

// fused conv2 normalization over sorted runs: z reduce + cs[src][cluster(dst)] += ew/z
__global__ __launch_bounds__(256) void k_znorm(
    const int2* __restrict__ es_se, const int* __restrict__ offs,
    const float* __restrict__ a_src2, const float* __restrict__ a_dst2,
    const int* __restrict__ assign, const float* __restrict__ cb,
    float* __restrict__ cs) {
    int t = threadIdx.x, lane = t & 63, wid = t >> 6;
    int g = lane >> 3, q = lane & 7;
    int n = (blockIdx.x * 4 + wid) * 8 + g;
    int o0 = offs[n], o1 = offs[n + 1];
    float adn = a_dst2[n];
    float c2 = cb[60];
    float z = 0.f;
    int s0 = 0; float ew0 = 0.f; bool v0 = false;
    for (int j = o0 + q; j < o1; j += 8) {
        int2 se = es_se[j];
        float lg = a_src2[se.x] + adn + __int_as_float(se.y) * c2;
        lg = lg >= 0.f ? lg : 0.2f * lg;
        float ew = __expf(lg);
        if (!v0) { s0 = se.x; ew0 = ew; v0 = true; }
        z += ew;
    }
    z += __shfl_xor(z, 1, 64);
    z += __shfl_xor(z, 2, 64);
    z += __shfl_xor(z, 4, 64);
    float rz = 1.f / z;          // no edges -> no adds below
    int c = assign[n];
    if (v0) atomicAdd(&cs[s0 * 4 + c], ew0 * rz);
    for (int j = o0 + q + 8; j < o1; j += 8) {
        int2 se = es_se[j];
        float lg = a_src2[se.x] + adn + __int_as_float(se.y) * c2;
        lg = lg >= 0.f ? lg : 0.2f * lg;
        atomicAdd(&cs[se.x * 4 + c], __expf(lg) * rz);
    }
}

// pooling as tiny GEMM: 8 lanes/node, 16B loads, register accumulators, direct gacc atomics
__global__ __launch_bounds__(256) void k_pool(
    const unsigned short* __restrict__ xh2b, const float* __restrict__ cs,
    const int* __restrict__ assign, const float* __restrict__ x,
    float* __restrict__ gacc) {
    __shared__ float csum[264];
    int t = threadIdx.x;
    int q = t & 7, slot = t >> 3;             // 32 node-slots per block
    float a0[8], a1[8], a2[8], a3[8];
    #pragma unroll
    for (int j = 0; j < 8; ++j) { a0[j] = 0.f; a1[j] = 0.f; a2[j] = 0.f; a3[j] = 0.f; }
    float cnt0 = 0.f, cnt1 = 0.f, cnt2 = 0.f, cnt3 = 0.f;
    float cf0 = 0.f, cf1 = 0.f, cf2 = 0.f, cf3 = 0.f;
    for (int n = blockIdx.x * 32 + slot; n < NN; n += NPB * 32) {
        uint4 u = *(const uint4*)(xh2b + n * 64 + q * 8);
        float4 c4 = *(const float4*)(cs + n * 4);
        float xv[8];
        xv[0] = bf2f((unsigned short)u.x); xv[1] = bf2f((unsigned short)(u.x >> 16));
        xv[2] = bf2f((unsigned short)u.y); xv[3] = bf2f((unsigned short)(u.y >> 16));
        xv[4] = bf2f((unsigned short)u.z); xv[5] = bf2f((unsigned short)(u.z >> 16));
        xv[6] = bf2f((unsigned short)u.w); xv[7] = bf2f((unsigned short)(u.w >> 16));
        #pragma unroll
        for (int j = 0; j < 8; ++j) {
            a0[j] = fmaf(c4.x, xv[j], a0[j]);
            a1[j] = fmaf(c4.y, xv[j], a1[j]);
            a2[j] = fmaf(c4.z, xv[j], a2[j]);
            a3[j] = fmaf(c4.w, xv[j], a3[j]);
        }
        if (q == 0) {
            int a = assign[n];
            float xf = x[n * 7 + 6];
            cnt0 += (a == 0) ? 1.f : 0.f;  cf0 += (a == 0) ? xf : 0.f;
            cnt1 += (a == 1) ? 1.f : 0.f;  cf1 += (a == 1) ? xf : 0.f;
            cnt2 += (a == 2) ? 1.f : 0.f;  cf2 += (a == 2) ? xf : 0.f;
            cnt3 += (a == 3) ? 1.f : 0.f;  cf3 += (a == 3) ? xf : 0.f;
        }
    }
    for (int i = t; i < 264; i += 256) csum[i] = 0.f;
    __syncthreads();
    int base = q * 8;
    #pragma unroll
    for (int j = 0; j < 8; ++j) {
        atomicAdd(&csum[0 * 64 + base + j], a0[j]);
        atomicAdd(&csum[1 * 64 + base + j], a1[j]);
        atomicAdd(&csum[2 * 64 + base + j], a2[j]);
        atomicAdd(&csum[3 * 64 + base + j], a3[j]);
    }
    if (q == 0) {
        atomicAdd(&csum[256], cnt0); atomicAdd(&csum[257], cnt1);
        atomicAdd(&csum[258], cnt2); atomicAdd(&csum[259], cnt3);
        atomicAdd(&csum[260], cf0);  atomicAdd(&csum[261], cf1);
        atomicAdd(&csum[262], cf2);  atomicAdd(&csum[263], cf3);
    }
    __syncthreads();
    for (int i = t; i < 264; i += 256) atomicAdd(&gacc[i], csum[i]);
}

// final head: cluster means (+cnt*b2), actor MLP + softmax, critic MLP
__global__ void k_head(const float* __restrict__ gacc, const float* __restrict__ b2,
                       const float* __restrict__ A1, const float* __restrict__ ba1,
                       const float* __restrict__ A2, const float* __restrict__ ba2,
                       const float* __restrict__ C1, const float* __restrict__ bc1,
                       const float* __restrict__ C2, const float* __restrict__ bc2,
                       float* __restrict__ out) {
    __shared__ float zc[4][64];
    __shared__ float cfs[4];
    __shared__ float logits[4];
    int j = threadIdx.x; // 64
    float b2j = b2[j];
    #pragma unroll
    for (int c = 0; c < 4; ++c) {
        float cnt = gacc[256 + c];
        float den = fmaxf(cnt, 1.f);
        zc[c][j] = (cnt > 0.f) ? (gacc[c * 64 + j] + cnt * b2j) / den : 0.f;
        if (j == 0) cfs[c] = (cnt > 0.f) ? gacc[260 + c] / den : 0.f;
    }
    __syncthreads();
    #pragma unroll
    for (int c = 0; c < 4; ++c) {
        float tv = ba1[j];
        for (int k = 0; k < 64; ++k) tv += zc[c][k] * A1[k * 64 + j];
        tv += cfs[c] * A1[64 * 64 + j];
        tv = fmaxf(tv, 0.f);
        float s = wave_reduce_sum(tv * A2[j]);
        if (j == 0) logits[c] = s + ba2[0];
    }
    float vj = bc1[j];
    for (int k = 0; k < 256; ++k) vj += zc[k >> 6][k & 63] * C1[k * 64 + j];
    vj = fmaxf(vj, 0.f);
    float v = wave_reduce_sum(vj * C2[j]);
    __syncthreads();
    if (j == 0) {
        float m = fmaxf(fmaxf(logits[0], logits[1]), fmaxf(logits[2], logits[3]));
        float e0 = __expf(logits[0] - m), e1 = __expf(logits[1] - m);
        float e2 = __expf(logits[2] - m), e3 = __expf(logits[3] - m);
        float sum = e0 + e1 + e2 + e3;
        out[0] = e0 / sum; out[1] = e1 / sum; out[2] = e2 / sum; out[3] = e3 / sum;
        out[4] = v + bc2[0];
    }
    #pragma unroll
    for (int c = 0; c < 4; ++c) out[5 + c * 64 + j] = zc[c][j];
}

extern "C" void kernel_launch(void* const* d_in, const int* in_sizes, int n_in,
                              void* d_out, int out_size, void* d_ws, size_t ws_size,
                              hipStream_t stream) {
    const float* x    = (const float*)d_in[0];
    const int*   ei   = (const int*)d_in[1];
    const float* ea   = (const float*)d_in[2];
    const int*   asg  = (const int*)d_in[3];
    const float* W1   = (const float*)d_in[4];
    const float* as1  = (const float*)d_in[5];
    const float* ad1  = (const float*)d_in[6];
    const float* We1  = (const float*)d_in[7];
    const float* ae1  = (const float*)d_in[8];
    const float* b1   = (const float*)d_in[9];
    const float* W2   = (const float*)d_in[10];
    const float* as2  = (const float*)d_in[11];
    const float* ad2  = (const float*)d_in[12];
    const float* We2  = (const float*)d_in[13];
    const float* ae2  = (const float*)d_in[14];
    const float* b2   = (const float*)d_in[15];
    const float* A1   = (const float*)d_in[16];
    const float* ba1  = (const float*)d_in[17];
    const float* A2   = (const float*)d_in[18];
    const float* ba2  = (const float*)d_in[19];
    const float* C1   = (const float*)d_in[20];
    const float* bc1  = (const float*)d_in[21];
    const float* C2   = (const float*)d_in[22];
    const float* bc2  = (const float*)d_in[23];
    const int* src = ei;
    const int* dst = ei + NE;

    char* w = (char*)d_ws;
    size_t off = 0;
    auto alloc = [&](size_t bytes) -> void* {
        void* p = w + off;
        off += (bytes + 255) & ~(size_t)255;
        return p;
    };
    // contiguous zero-init region: hist | cs | gacc
    int*   hist   = (int*)alloc(NN * sizeof(int));
    float* cs     = (float*)alloc(NN * 4 * sizeof(float));
    float* gacc   = (float*)alloc(264 * sizeof(float));
    size_t zspan  = (size_t)((char*)gacc + 264 * sizeof(float) - (char*)hist);
    float* a_src1 = (float*)alloc(NN * 4 * sizeof(float));
    float* a_dst1 = (float*)alloc(NN * 4 * sizeof(float));
    float* a_src2 = (float*)alloc(NN * sizeof(float));
    float* a_dst2 = (float*)alloc(NN * sizeof(float));
    float* x8g    = (float*)alloc(NN * 8 * sizeof(float));
    int*   offs   = (int*)alloc((NN + 1) * sizeof(int));
    int*   cursor = (int*)alloc(NN * sizeof(int));
    int*   bsum   = (int*)alloc(128 * sizeof(int));
    int*   bexcl  = (int*)alloc(128 * sizeof(int));
    int2*  es_se  = (int2*)alloc(NE * sizeof(int2));
    unsigned short* xh2b = (unsigned short*)alloc(NN * 64 * sizeof(unsigned short));
    unsigned short* W2fr = (unsigned short*)alloc(16384 * sizeof(unsigned short));
    float* cb     = (float*)alloc(64 * sizeof(float));
    (void)ws_size; (void)n_in; (void)in_sizes; (void)out_size;

    hipMemsetAsync(hist, 0, zspan, stream);

    k_pre<<<65, 256, 0, stream>>>(W1, as1, ad1, We1, ae1, We2, ae2, W2, cb, W2fr);
    k_node1h<<<(NN + 255) / 256, 256, 0, stream>>>(x, cb, dst, a_src1, a_dst1, x8g, hist);
    k_scanA<<<98, 1024, 0, stream>>>(hist, bsum);
    k_scanB<<<1, 128, 0, stream>>>(bsum, bexcl);
    k_scanC<<<98, 1024, 0, stream>>>(hist, bexcl, offs, cursor);
    k_scatter<<<(NE + 255) / 256, 256, 0, stream>>>(src, dst, ea, cursor, es_se);
    k_conv1red<<<NN / 32, 256, 0, stream>>>(x8g, W1, b1, cb, offs, es_se, a_src1, a_dst1,
                                            as2, ad2, W2fr, xh2b, a_src2, a_dst2);
    k_znorm<<<NN / 32, 256, 0, stream>>>(es_se, offs, a_src2, a_dst2, asg, cb, cs);
    k_pool<<<NPB, 256, 0, stream>>>(xh2b, cs, asg, x, gacc);
    k_head<<<1, 64, 0, stream>>>(gacc, b2, A1, ba1, A2, ba2, C1, bc1, C2, bc2, (float*)d_out);
}

// Round 9
// 225.076 us; speedup vs baseline: 1.4956x; 1.0894x over previous
//
#include <hip/hip_runtime.h>

#define NN 100000
#define NE 800000
#define NPB 512   // k_pool blocks
#define SRCMASK 0x01FFFFFF

typedef short bf16x8 __attribute__((ext_vector_type(8)));
typedef float f32x4 __attribute__((ext_vector_type(4)));

__device__ __forceinline__ float wave_reduce_sum(float v) {
    #pragma unroll
    for (int o = 32; o > 0; o >>= 1) v += __shfl_down(v, o, 64);
    return v; // valid in lane 0
}

__device__ __forceinline__ unsigned short f2bf(float f) {
    unsigned u = __float_as_uint(f);
    unsigned r = (u + 0x7FFFu + ((u >> 16) & 1u)) >> 16;
    return (unsigned short)r;
}
__device__ __forceinline__ float bf2f(unsigned short b) {
    return __uint_as_float(((unsigned)b) << 16);
}

// cb layout (floats): [0..27] vs1(k*4+h)  [28..55] vd1  [56..59] c1[h]  [60] c2
__global__ void k_pre(const float* __restrict__ W1, const float* __restrict__ as1,
                      const float* __restrict__ ad1,
                      const float* __restrict__ We1, const float* __restrict__ ae1,
                      const float* __restrict__ We2, const float* __restrict__ ae2,
                      const float* __restrict__ W2,
                      float* __restrict__ cb, unsigned short* __restrict__ W2fr) {
    int t = threadIdx.x;
    if (blockIdx.x == 0) {
        if (t < 28) {
            int k = t >> 2, h = t & 3;
            float s = 0.f, d = 0.f;
            for (int c = 0; c < 64; ++c) {
                float w = W1[k * 256 + h * 64 + c];
                s += w * as1[h * 64 + c];
                d += w * ad1[h * 64 + c];
            }
            cb[t] = s; cb[28 + t] = d;
        } else if (t < 32) {
            int h = t - 28;
            float s = 0.f;
            for (int c = 0; c < 64; ++c) s += We1[h * 64 + c] * ae1[h * 64 + c];
            cb[56 + h] = s;
        } else if (t == 32) {
            float s = 0.f;
            for (int c = 0; c < 64; ++c) s += We2[c] * ae2[c];
            cb[60] = s;
        }
    } else {
        int o = (blockIdx.x - 1) * 256 + t;        // 0..16383
        int i = o & 7, l = (o >> 3) & 63, ct = (o >> 9) & 3, ks = o >> 11;
        int k = ks * 32 + ((l >> 4) * 8) + i;
        int col = ct * 16 + (l & 15);
        W2fr[o] = f2bf(W2[k * 64 + col]);
    }
}

// per-node: conv1 attention coefficients + packed bf16 x-record; fused dst histogram
__global__ void k_node1h(const float* __restrict__ x, const float* __restrict__ cb,
                         const int* __restrict__ dst,
                         float* __restrict__ a_src1, float* __restrict__ a_dst1,
                         uint4* __restrict__ xpack, int* __restrict__ hist) {
    int n = blockIdx.x * 256 + threadIdx.x;
    if (n >= NN) return;
    float xv[7];
    #pragma unroll
    for (int k = 0; k < 7; ++k) xv[k] = x[n * 7 + k];
    float s[4] = {0.f, 0.f, 0.f, 0.f}, d[4] = {0.f, 0.f, 0.f, 0.f};
    #pragma unroll
    for (int k = 0; k < 7; ++k)
        #pragma unroll
        for (int h = 0; h < 4; ++h) {
            s[h] += xv[k] * cb[k * 4 + h];
            d[h] += xv[k] * cb[28 + k * 4 + h];
        }
    *(float4*)(a_src1 + n * 4) = make_float4(s[0], s[1], s[2], s[3]);
    *(float4*)(a_dst1 + n * 4) = make_float4(d[0], d[1], d[2], d[3]);
    unsigned p0 = (unsigned)f2bf(xv[0]) | ((unsigned)f2bf(xv[1]) << 16);
    unsigned p1 = (unsigned)f2bf(xv[2]) | ((unsigned)f2bf(xv[3]) << 16);
    unsigned p2 = (unsigned)f2bf(xv[4]) | ((unsigned)f2bf(xv[5]) << 16);
    unsigned p3 = (unsigned)f2bf(xv[6]) | ((unsigned)f2bf(1.f) << 16);
    xpack[n] = make_uint4(p0, p1, p2, p3);
    // histogram: edges [n*8, n*8+8)
    int e0 = n * 8;
    int4 d0 = *(const int4*)(dst + e0);
    int4 d1 = *(const int4*)(dst + e0 + 4);
    atomicAdd(&hist[d0.x], 1); atomicAdd(&hist[d0.y], 1);
    atomicAdd(&hist[d0.z], 1); atomicAdd(&hist[d0.w], 1);
    atomicAdd(&hist[d1.x], 1); atomicAdd(&hist[d1.y], 1);
    atomicAdd(&hist[d1.z], 1); atomicAdd(&hist[d1.w], 1);
}

// --- 3-phase parallel exclusive scan over hist[NN] -> offs[NN+1], cursor[NN] ---
__global__ __launch_bounds__(1024) void k_scanA(const int* __restrict__ hist,
                                                int* __restrict__ bsum) {
    __shared__ int ws[16];
    int i = blockIdx.x * 1024 + threadIdx.x;
    int lane = threadIdx.x & 63, wid = threadIdx.x >> 6;
    int v = (i < NN) ? hist[i] : 0;
    #pragma unroll
    for (int o = 32; o; o >>= 1) v += __shfl_down(v, o, 64);
    if (lane == 0) ws[wid] = v;
    __syncthreads();
    if (wid == 0) {
        int u = (lane < 16) ? ws[lane] : 0;
        #pragma unroll
        for (int o = 8; o; o >>= 1) u += __shfl_down(u, o, 64);
        if (lane == 0) bsum[blockIdx.x] = u;
    }
}

__global__ void k_scanB(const int* __restrict__ bsum, int* __restrict__ bexcl) {
    __shared__ int w0tot;
    int t = threadIdx.x, lane = t & 63, wid = t >> 6;
    int v = (t < 98) ? bsum[t] : 0;
    int s = v;
    #pragma unroll
    for (int d = 1; d < 64; d <<= 1) { int u = __shfl_up(s, d, 64); if (lane >= d) s += u; }
    if (t == 63) w0tot = s;
    __syncthreads();
    if (wid == 1) s += w0tot;
    if (t < 98) bexcl[t] = s - v;
}

__global__ __launch_bounds__(1024) void k_scanC(const int* __restrict__ hist,
                                                const int* __restrict__ bexcl,
                                                int* __restrict__ offs,
                                                int* __restrict__ cursor) {
    __shared__ int ws[16];
    int b = blockIdx.x;
    int i = b * 1024 + threadIdx.x;
    int lane = threadIdx.x & 63, wid = threadIdx.x >> 6;
    int v = (i < NN) ? hist[i] : 0;
    int s = v;
    #pragma unroll
    for (int d = 1; d < 64; d <<= 1) { int u = __shfl_up(s, d, 64); if (lane >= d) s += u; }
    if (lane == 63) ws[wid] = s;
    __syncthreads();
    if (wid == 0) {
        int u2 = (lane < 16) ? ws[lane] : 0;
        #pragma unroll
        for (int d = 1; d < 16; d <<= 1) { int uu = __shfl_up(u2, d, 64); if (lane >= d) u2 += uu; }
        if (lane < 16) ws[lane] = u2;
    }
    __syncthreads();
    int incl = s + (wid ? ws[wid - 1] : 0) + bexcl[b];
    if (i < NN) { offs[i + 1] = incl; cursor[i] = incl - v; }
    if (i == 0) offs[0] = 0;
}

// scatter + conv1 edge weights: es2[pos] = {w01, w23 (bf16x4), src|(dst&31)<<25, ea}
__global__ void k_scatter(const int* __restrict__ src, const int* __restrict__ dst,
                          const float* __restrict__ ea,
                          const float* __restrict__ a_src1, const float* __restrict__ a_dst1,
                          const float* __restrict__ cb,
                          int* __restrict__ cursor, int4* __restrict__ es2) {
    int e = blockIdx.x * 256 + threadIdx.x;
    if (e >= NE) return;
    int s = src[e], d = dst[e];
    float eav = ea[e];
    int pos = atomicAdd(&cursor[d], 1);
    float4 as_ = *(const float4*)(a_src1 + s * 4);
    float4 ad_ = *(const float4*)(a_dst1 + d * 4);
    float lg0 = as_.x + ad_.x + eav * cb[56];
    float lg1 = as_.y + ad_.y + eav * cb[57];
    float lg2 = as_.z + ad_.z + eav * cb[58];
    float lg3 = as_.w + ad_.w + eav * cb[59];
    lg0 = lg0 >= 0.f ? lg0 : 0.2f * lg0;
    lg1 = lg1 >= 0.f ? lg1 : 0.2f * lg1;
    lg2 = lg2 >= 0.f ? lg2 : 0.2f * lg2;
    lg3 = lg3 >= 0.f ? lg3 : 0.2f * lg3;
    unsigned w01 = (unsigned)f2bf(__expf(lg0)) | ((unsigned)f2bf(__expf(lg1)) << 16);
    unsigned w23 = (unsigned)f2bf(__expf(lg2)) | ((unsigned)f2bf(__expf(lg3)) << 16);
    es2[pos] = make_int4((int)w01, (int)w23, s | ((d & 31) << 25), __float_as_int(eav));
}

// fused conv1: two-phase LDS-staged segmented reduce -> h -> MFMA (xh2 + a_src2/a_dst2 epilogue)
__global__ __launch_bounds__(256) void k_conv1red(
    const uint4* __restrict__ xpack, const float* __restrict__ W1, const float* __restrict__ b1,
    const int* __restrict__ offs, const int4* __restrict__ es2,
    const float* __restrict__ as2, const float* __restrict__ ad2,
    const unsigned short* __restrict__ W2fr,
    unsigned short* __restrict__ xh2b, float* __restrict__ a_src2, float* __restrict__ a_dst2) {
    __shared__ int soffs[33];
    __shared__ float sacc[32], dacc[32];
    __shared__ float xw[256][13];
    __shared__ float ms[32][33];
    __shared__ __attribute__((aligned(16))) unsigned short hs[32][264];
    int t = threadIdx.x, lane = t & 63, wid = t >> 6;
    int n0 = blockIdx.x * 32;
    if (t <= 32) soffs[t] = offs[n0 + t];
    if (t < 32) { sacc[t] = 0.f; dacc[t] = 0.f; }
    float w1r[7][4], b1r[4];
    #pragma unroll
    for (int k = 0; k < 7; ++k)
        #pragma unroll
        for (int h = 0; h < 4; ++h) w1r[k][h] = W1[k * 256 + h * 64 + lane];
    #pragma unroll
    for (int h = 0; h < 4; ++h) b1r[h] = b1[h * 64 + lane];
    __syncthreads();
    int E0 = soffs[0], E1 = soffs[32];
    int g = t >> 3, q = t & 7;
    int go0 = soffs[g], go1 = soffs[g + 1];
    float mh0 = 0.f, mh1 = 0.f, mh2 = 0.f, mh3 = 0.f;
    for (int C0 = E0; C0 < E1; C0 += 256) {
        int C1 = min(C0 + 256, E1);
        int j = C0 + t;
        if (j < C1) {
            int4 e4 = es2[j];
            int s = e4.z & SRCMASK;
            uint4 xp = xpack[s];
            xw[t][0] = bf2f((unsigned short)xp.x);
            xw[t][1] = bf2f((unsigned short)(xp.x >> 16));
            xw[t][2] = bf2f((unsigned short)xp.y);
            xw[t][3] = bf2f((unsigned short)(xp.y >> 16));
            xw[t][4] = bf2f((unsigned short)xp.z);
            xw[t][5] = bf2f((unsigned short)(xp.z >> 16));
            xw[t][6] = bf2f((unsigned short)xp.w);
            xw[t][7] = bf2f((unsigned short)(xp.w >> 16));
            xw[t][8] = bf2f((unsigned short)e4.x);
            xw[t][9] = bf2f((unsigned short)(((unsigned)e4.x) >> 16));
            xw[t][10] = bf2f((unsigned short)e4.y);
            xw[t][11] = bf2f((unsigned short)(((unsigned)e4.y) >> 16));
        }
        __syncthreads();
        int lo = max(go0, C0) - C0, hi = min(go1, C1) - C0;
        for (int jj = lo; jj < hi; ++jj) {
            float xv = xw[jj][q];
            mh0 = fmaf(xw[jj][8], xv, mh0);
            mh1 = fmaf(xw[jj][9], xv, mh1);
            mh2 = fmaf(xw[jj][10], xv, mh2);
            mh3 = fmaf(xw[jj][11], xv, mh3);
        }
        __syncthreads();
    }
    ms[g][0 * 8 + q] = mh0; ms[g][1 * 8 + q] = mh1;
    ms[g][2 * 8 + q] = mh2; ms[g][3 * 8 + q] = mh3;
    __syncthreads();
    // finish: 8 nodes per wave, lane = channel
    for (int gi = wid * 8; gi < wid * 8 + 8; ++gi) {
        bool has = soffs[gi + 1] > soffs[gi];
        #pragma unroll
        for (int h = 0; h < 4; ++h) {
            float z = ms[gi][h * 8 + 7];
            float a = 0.f;
            #pragma unroll
            for (int k = 0; k < 7; ++k) a = fmaf(ms[gi][h * 8 + k], w1r[k][h], a);
            float mm = (has ? a / z : 0.f) + b1r[h];
            float hv = mm > 0.f ? mm : (__expf(mm) - 1.f);
            hs[gi][h * 64 + lane] = f2bf(hv);
        }
    }
    __syncthreads();
    // MFMA: 2 node-tiles x 4 col-tiles; epilogue computes a_src2/a_dst2 from acc
    int row = lane & 15, kg = lane >> 4;
    #pragma unroll
    for (int u = wid; u < 8; u += 4) {
        int nt = u & 1, ct = u >> 1;
        f32x4 acc = {0.f, 0.f, 0.f, 0.f};
        #pragma unroll
        for (int ks = 0; ks < 8; ++ks) {
            bf16x8 av = *(const bf16x8*)&hs[nt * 16 + row][ks * 32 + kg * 8];
            bf16x8 bv = *(const bf16x8*)(W2fr + (((ks * 4 + ct) * 64) + lane) * 8);
            acc = __builtin_amdgcn_mfma_f32_16x16x32_bf16(av, bv, acc, 0, 0, 0);
        }
        float as2v = as2[ct * 16 + row];
        float ad2v = ad2[ct * 16 + row];
        #pragma unroll
        for (int i = 0; i < 4; ++i) {
            xh2b[(n0 + nt * 16 + kg * 4 + i) * 64 + ct * 16 + row] = f2bf(acc[i]);
            float ps = acc[i] * as2v;
            float pd = acc[i] * ad2v;
            #pragma unroll
            for (int o = 1; o < 16; o <<= 1) {
                ps += __shfl_xor(ps, o, 64);
                pd += __shfl_xor(pd, o, 64);
            }
            if (row == 0) {
                atomicAdd(&sacc[nt * 16 + kg * 4 + i], ps);
                atomicAdd(&dacc[nt * 16 + kg * 4 + i], pd);
            }
        }
    }
    __syncthreads();
    if (t < 32) {
        a_src2[n0 + t] = sacc[t];
        a_dst2[n0 + t] = dacc[t];
    }
}

// fused conv2 normalization over sorted runs: z reduce + cs[src][cluster(dst)] += ew/z
__global__ __launch_bounds__(256) void k_znorm(
    const int4* __restrict__ es2, const int* __restrict__ offs,
    const float* __restrict__ a_src2, const float* __restrict__ a_dst2,
    const int* __restrict__ assign, const float* __restrict__ cb,
    float* __restrict__ cs) {
    int t = threadIdx.x, lane = t & 63, wid = t >> 6;
    int g = lane >> 3, q = lane & 7;
    int n = (blockIdx.x * 4 + wid) * 8 + g;
    int o0 = offs[n], o1 = offs[n + 1];
    float adn = a_dst2[n];
    float c2 = cb[60];
    float z = 0.f;
    int s0 = 0; float ew0 = 0.f; bool v0 = false;
    for (int j = o0 + q; j < o1; j += 8) {
        int4 se = es2[j];
        int sx = se.z & SRCMASK;
        float lg = a_src2[sx] + adn + __int_as_float(se.w) * c2;
        lg = lg >= 0.f ? lg : 0.2f * lg;
        float ew = __expf(lg);
        if (!v0) { s0 = sx; ew0 = ew; v0 = true; }
        z += ew;
    }
    z += __shfl_xor(z, 1, 64);
    z += __shfl_xor(z, 2, 64);
    z += __shfl_xor(z, 4, 64);
    float rz = 1.f / z;          // no edges -> no adds below
    int c = assign[n];
    if (v0) atomicAdd(&cs[s0 * 4 + c], ew0 * rz);
    for (int j = o0 + q + 8; j < o1; j += 8) {
        int4 se = es2[j];
        int sx = se.z & SRCMASK;
        float lg = a_src2[sx] + adn + __int_as_float(se.w) * c2;
        lg = lg >= 0.f ? lg : 0.2f * lg;
        atomicAdd(&cs[sx * 4 + c], __expf(lg) * rz);
    }
}

// pooling as tiny GEMM: 8 lanes/node, 16B loads, register accumulators, direct gacc atomics
__global__ __launch_bounds__(256) void k_pool(
    const unsigned short* __restrict__ xh2b, const float* __restrict__ cs,
    const int* __restrict__ assign, const float* __restrict__ x,
    float* __restrict__ gacc) {
    __shared__ float csum[264];
    int t = threadIdx.x;
    int q = t & 7, slot = t >> 3;             // 32 node-slots per block
    float a0[8], a1[8], a2[8], a3[8];
    #pragma unroll
    for (int j = 0; j < 8; ++j) { a0[j] = 0.f; a1[j] = 0.f; a2[j] = 0.f; a3[j] = 0.f; }
    float cnt0 = 0.f, cnt1 = 0.f, cnt2 = 0.f, cnt3 = 0.f;
    float cf0 = 0.f, cf1 = 0.f, cf2 = 0.f, cf3 = 0.f;
    for (int n = blockIdx.x * 32 + slot; n < NN; n += NPB * 32) {
        uint4 u = *(const uint4*)(xh2b + n * 64 + q * 8);
        float4 c4 = *(const float4*)(cs + n * 4);
        float xv[8];
        xv[0] = bf2f((unsigned short)u.x); xv[1] = bf2f((unsigned short)(u.x >> 16));
        xv[2] = bf2f((unsigned short)u.y); xv[3] = bf2f((unsigned short)(u.y >> 16));
        xv[4] = bf2f((unsigned short)u.z); xv[5] = bf2f((unsigned short)(u.z >> 16));
        xv[6] = bf2f((unsigned short)u.w); xv[7] = bf2f((unsigned short)(u.w >> 16));
        #pragma unroll
        for (int j = 0; j < 8; ++j) {
            a0[j] = fmaf(c4.x, xv[j], a0[j]);
            a1[j] = fmaf(c4.y, xv[j], a1[j]);
            a2[j] = fmaf(c4.z, xv[j], a2[j]);
            a3[j] = fmaf(c4.w, xv[j], a3[j]);
        }
        if (q == 0) {
            int a = assign[n];
            float xf = x[n * 7 + 6];
            cnt0 += (a == 0) ? 1.f : 0.f;  cf0 += (a == 0) ? xf : 0.f;
            cnt1 += (a == 1) ? 1.f : 0.f;  cf1 += (a == 1) ? xf : 0.f;
            cnt2 += (a == 2) ? 1.f : 0.f;  cf2 += (a == 2) ? xf : 0.f;
            cnt3 += (a == 3) ? 1.f : 0.f;  cf3 += (a == 3) ? xf : 0.f;
        }
    }
    for (int i = t; i < 264; i += 256) csum[i] = 0.f;
    __syncthreads();
    int base = q * 8;
    #pragma unroll
    for (int j = 0; j < 8; ++j) {
        atomicAdd(&csum[0 * 64 + base + j], a0[j]);
        atomicAdd(&csum[1 * 64 + base + j], a1[j]);
        atomicAdd(&csum[2 * 64 + base + j], a2[j]);
        atomicAdd(&csum[3 * 64 + base + j], a3[j]);
    }
    if (q == 0) {
        atomicAdd(&csum[256], cnt0); atomicAdd(&csum[257], cnt1);
        atomicAdd(&csum[258], cnt2); atomicAdd(&csum[259], cnt3);
        atomicAdd(&csum[260], cf0);  atomicAdd(&csum[261], cf1);
        atomicAdd(&csum[262], cf2);  atomicAdd(&csum[263], cf3);
    }
    __syncthreads();
    for (int i = t; i < 264; i += 256) atomicAdd(&gacc[i], csum[i]);
}

// final head (256 threads): cluster means (+cnt*b2), actor MLP + softmax, critic MLP
__global__ __launch_bounds__(256) void k_head(
    const float* __restrict__ gacc, const float* __restrict__ b2,
    const float* __restrict__ A1, const float* __restrict__ ba1,
    const float* __restrict__ A2, const float* __restrict__ ba2,
    const float* __restrict__ C1, const float* __restrict__ bc1,
    const float* __restrict__ C2, const float* __restrict__ bc2,
    float* __restrict__ out) {
    __shared__ float zc[4][64];
    __shared__ float cfs[4];
    __shared__ float logits[4];
    __shared__ float vpart[4][64];
    int t = threadIdx.x;
    int j = t & 63, wv = t >> 6;   // wave wv handles cluster wv
    float cnt = gacc[256 + wv];
    float den = fmaxf(cnt, 1.f);
    zc[wv][j] = (cnt > 0.f) ? (gacc[wv * 64 + j] + cnt * b2[j]) / den : 0.f;
    if (t < 4) {
        float cc = gacc[256 + t];
        cfs[t] = (cc > 0.f) ? gacc[260 + t] / fmaxf(cc, 1.f) : 0.f;
    }
    __syncthreads();
    // actor: cluster wv
    float tv = ba1[j];
    for (int k = 0; k < 64; ++k) tv = fmaf(zc[wv][k], A1[k * 64 + j], tv);
    tv = fmaf(cfs[wv], A1[64 * 64 + j], tv);
    tv = fmaxf(tv, 0.f);
    float sred = wave_reduce_sum(tv * A2[j]);
    if (j == 0) logits[wv] = sred + ba2[0];
    // critic partials: wave wv covers k in [wv*64, (wv+1)*64)
    float vj = (wv == 0) ? bc1[j] : 0.f;
    for (int kk = 0; kk < 64; ++kk) vj = fmaf(zc[wv][kk], C1[(wv * 64 + kk) * 64 + j], vj);
    vpart[wv][j] = vj;
    __syncthreads();
    if (wv == 0) {
        float vv = fmaxf(vpart[0][j] + vpart[1][j] + vpart[2][j] + vpart[3][j], 0.f);
        float v = wave_reduce_sum(vv * C2[j]);
        if (j == 0) {
            float m = fmaxf(fmaxf(logits[0], logits[1]), fmaxf(logits[2], logits[3]));
            float e0 = __expf(logits[0] - m), e1 = __expf(logits[1] - m);
            float e2 = __expf(logits[2] - m), e3 = __expf(logits[3] - m);
            float sum = e0 + e1 + e2 + e3;
            out[0] = e0 / sum; out[1] = e1 / sum; out[2] = e2 / sum; out[3] = e3 / sum;
            out[4] = v + bc2[0];
        }
    }
    out[5 + wv * 64 + j] = zc[wv][j];
}

extern "C" void kernel_launch(void* const* d_in, const int* in_sizes, int n_in,
                              void* d_out, int out_size, void* d_ws, size_t ws_size,
                              hipStream_t stream) {
    const float* x    = (const float*)d_in[0];
    const int*   ei   = (const int*)d_in[1];
    const float* ea   = (const float*)d_in[2];
    const int*   asg  = (const int*)d_in[3];
    const float* W1   = (const float*)d_in[4];
    const float* as1  = (const float*)d_in[5];
    const float* ad1  = (const float*)d_in[6];
    const float* We1  = (const float*)d_in[7];
    const float* ae1  = (const float*)d_in[8];
    const float* b1   = (const float*)d_in[9];
    const float* W2   = (const float*)d_in[10];
    const float* as2  = (const float*)d_in[11];
    const float* ad2  = (const float*)d_in[12];
    const float* We2  = (const float*)d_in[13];
    const float* ae2  = (const float*)d_in[14];
    const float* b2   = (const float*)d_in[15];
    const float* A1   = (const float*)d_in[16];
    const float* ba1  = (const float*)d_in[17];
    const float* A2   = (const float*)d_in[18];
    const float* ba2  = (const float*)d_in[19];
    const float* C1   = (const float*)d_in[20];
    const float* bc1  = (const float*)d_in[21];
    const float* C2   = (const float*)d_in[22];
    const float* bc2  = (const float*)d_in[23];
    const int* src = ei;
    const int* dst = ei + NE;

    char* w = (char*)d_ws;
    size_t off = 0;
    auto alloc = [&](size_t bytes) -> void* {
        void* p = w + off;
        off += (bytes + 255) & ~(size_t)255;
        return p;
    };
    // contiguous zero-init region: hist | cs | gacc
    int*   hist   = (int*)alloc(NN * sizeof(int));
    float* cs     = (float*)alloc(NN * 4 * sizeof(float));
    float* gacc   = (float*)alloc(264 * sizeof(float));
    size_t zspan  = (size_t)((char*)gacc + 264 * sizeof(float) - (char*)hist);
    float* a_src1 = (float*)alloc(NN * 4 * sizeof(float));
    float* a_dst1 = (float*)alloc(NN * 4 * sizeof(float));
    float* a_src2 = (float*)alloc(NN * sizeof(float));
    float* a_dst2 = (float*)alloc(NN * sizeof(float));
    uint4* xpack  = (uint4*)alloc(NN * sizeof(uint4));
    int*   offs   = (int*)alloc((NN + 1) * sizeof(int));
    int*   cursor = (int*)alloc(NN * sizeof(int));
    int*   bsum   = (int*)alloc(128 * sizeof(int));
    int*   bexcl  = (int*)alloc(128 * sizeof(int));
    int4*  es2    = (int4*)alloc(NE * sizeof(int4));
    unsigned short* xh2b = (unsigned short*)alloc(NN * 64 * sizeof(unsigned short));
    unsigned short* W2fr = (unsigned short*)alloc(16384 * sizeof(unsigned short));
    float* cb     = (float*)alloc(64 * sizeof(float));
    (void)ws_size; (void)n_in; (void)in_sizes; (void)out_size;

    hipMemsetAsync(hist, 0, zspan, stream);

    k_pre<<<65, 256, 0, stream>>>(W1, as1, ad1, We1, ae1, We2, ae2, W2, cb, W2fr);
    k_node1h<<<(NN + 255) / 256, 256, 0, stream>>>(x, cb, dst, a_src1, a_dst1, xpack, hist);
    k_scanA<<<98, 1024, 0, stream>>>(hist, bsum);
    k_scanB<<<1, 128, 0, stream>>>(bsum, bexcl);
    k_scanC<<<98, 1024, 0, stream>>>(hist, bexcl, offs, cursor);
    k_scatter<<<(NE + 255) / 256, 256, 0, stream>>>(src, dst, ea, a_src1, a_dst1, cb,
                                                    cursor, es2);
    k_conv1red<<<NN / 32, 256, 0, stream>>>(xpack, W1, b1, offs, es2,
                                            as2, ad2, W2fr, xh2b, a_src2, a_dst2);
    k_znorm<<<NN / 32, 256, 0, stream>>>(es2, offs, a_src2, a_dst2, asg, cb, cs);
    k_pool<<<NPB, 256, 0, stream>>>(xh2b, cs, asg, x, gacc);
    k_head<<<1, 256, 0, stream>>>(gacc, b2, A1, ba1, A2, ba2, C1, bc1, C2, bc2, (float*)d_out);
}

// Round 10
// 219.863 us; speedup vs baseline: 1.5311x; 1.0237x over previous
//
#include <hip/hip_runtime.h>

#define NN 100000
#define NE 800000
#define NPB 512   // k_pool blocks
#define SRCMASK 0x01FFFFFF

typedef short bf16x8 __attribute__((ext_vector_type(8)));
typedef float f32x4 __attribute__((ext_vector_type(4)));

__device__ __forceinline__ float wave_reduce_sum(float v) {
    #pragma unroll
    for (int o = 32; o > 0; o >>= 1) v += __shfl_down(v, o, 64);
    return v; // valid in lane 0
}

__device__ __forceinline__ unsigned short f2bf(float f) {
    unsigned u = __float_as_uint(f);
    unsigned r = (u + 0x7FFFu + ((u >> 16) & 1u)) >> 16;
    return (unsigned short)r;
}
__device__ __forceinline__ float bf2f(unsigned short b) {
    return __uint_as_float(((unsigned)b) << 16);
}
__device__ __forceinline__ float bflo(unsigned u) {   // low bf16 of u32
    return __uint_as_float(u << 16);
}
__device__ __forceinline__ float bfhi(unsigned u) {   // high bf16 of u32
    return __uint_as_float(u & 0xFFFF0000u);
}

// cb layout (floats): [0..27] vs1(k*4+h)  [28..55] vd1  [56..59] c1[h]  [60] c2
__global__ void k_pre(const float* __restrict__ W1, const float* __restrict__ as1,
                      const float* __restrict__ ad1,
                      const float* __restrict__ We1, const float* __restrict__ ae1,
                      const float* __restrict__ We2, const float* __restrict__ ae2,
                      const float* __restrict__ W2,
                      float* __restrict__ cb, unsigned short* __restrict__ W2fr) {
    int t = threadIdx.x;
    if (blockIdx.x == 0) {
        if (t < 28) {
            int k = t >> 2, h = t & 3;
            float s = 0.f, d = 0.f;
            for (int c = 0; c < 64; ++c) {
                float w = W1[k * 256 + h * 64 + c];
                s += w * as1[h * 64 + c];
                d += w * ad1[h * 64 + c];
            }
            cb[t] = s; cb[28 + t] = d;
        } else if (t < 32) {
            int h = t - 28;
            float s = 0.f;
            for (int c = 0; c < 64; ++c) s += We1[h * 64 + c] * ae1[h * 64 + c];
            cb[56 + h] = s;
        } else if (t == 32) {
            float s = 0.f;
            for (int c = 0; c < 64; ++c) s += We2[c] * ae2[c];
            cb[60] = s;
        }
    } else {
        int o = (blockIdx.x - 1) * 256 + t;        // 0..16383
        int i = o & 7, l = (o >> 3) & 63, ct = (o >> 9) & 3, ks = o >> 11;
        int k = ks * 32 + ((l >> 4) * 8) + i;
        int col = ct * 16 + (l & 15);
        W2fr[o] = f2bf(W2[k * 64 + col]);
    }
}

// per-node: conv1 attention coefficients + packed bf16 x-record; fused dst histogram
__global__ void k_node1h(const float* __restrict__ x, const float* __restrict__ cb,
                         const int* __restrict__ dst,
                         float* __restrict__ a_src1, float* __restrict__ a_dst1,
                         uint4* __restrict__ xpack, int* __restrict__ hist) {
    int n = blockIdx.x * 256 + threadIdx.x;
    if (n >= NN) return;
    float xv[7];
    #pragma unroll
    for (int k = 0; k < 7; ++k) xv[k] = x[n * 7 + k];
    float s[4] = {0.f, 0.f, 0.f, 0.f}, d[4] = {0.f, 0.f, 0.f, 0.f};
    #pragma unroll
    for (int k = 0; k < 7; ++k)
        #pragma unroll
        for (int h = 0; h < 4; ++h) {
            s[h] += xv[k] * cb[k * 4 + h];
            d[h] += xv[k] * cb[28 + k * 4 + h];
        }
    *(float4*)(a_src1 + n * 4) = make_float4(s[0], s[1], s[2], s[3]);
    *(float4*)(a_dst1 + n * 4) = make_float4(d[0], d[1], d[2], d[3]);
    unsigned p0 = (unsigned)f2bf(xv[0]) | ((unsigned)f2bf(xv[1]) << 16);
    unsigned p1 = (unsigned)f2bf(xv[2]) | ((unsigned)f2bf(xv[3]) << 16);
    unsigned p2 = (unsigned)f2bf(xv[4]) | ((unsigned)f2bf(xv[5]) << 16);
    unsigned p3 = (unsigned)f2bf(xv[6]) | ((unsigned)f2bf(1.f) << 16);
    xpack[n] = make_uint4(p0, p1, p2, p3);
    // histogram: edges [n*8, n*8+8)
    int e0 = n * 8;
    int4 d0 = *(const int4*)(dst + e0);
    int4 d1 = *(const int4*)(dst + e0 + 4);
    atomicAdd(&hist[d0.x], 1); atomicAdd(&hist[d0.y], 1);
    atomicAdd(&hist[d0.z], 1); atomicAdd(&hist[d0.w], 1);
    atomicAdd(&hist[d1.x], 1); atomicAdd(&hist[d1.y], 1);
    atomicAdd(&hist[d1.z], 1); atomicAdd(&hist[d1.w], 1);
}

// --- 3-phase parallel exclusive scan over hist[NN] -> offs[NN+1], cursor[NN] ---
__global__ __launch_bounds__(1024) void k_scanA(const int* __restrict__ hist,
                                                int* __restrict__ bsum) {
    __shared__ int ws[16];
    int i = blockIdx.x * 1024 + threadIdx.x;
    int lane = threadIdx.x & 63, wid = threadIdx.x >> 6;
    int v = (i < NN) ? hist[i] : 0;
    #pragma unroll
    for (int o = 32; o; o >>= 1) v += __shfl_down(v, o, 64);
    if (lane == 0) ws[wid] = v;
    __syncthreads();
    if (wid == 0) {
        int u = (lane < 16) ? ws[lane] : 0;
        #pragma unroll
        for (int o = 8; o; o >>= 1) u += __shfl_down(u, o, 64);
        if (lane == 0) bsum[blockIdx.x] = u;
    }
}

__global__ void k_scanB(const int* __restrict__ bsum, int* __restrict__ bexcl) {
    __shared__ int w0tot;
    int t = threadIdx.x, lane = t & 63, wid = t >> 6;
    int v = (t < 98) ? bsum[t] : 0;
    int s = v;
    #pragma unroll
    for (int d = 1; d < 64; d <<= 1) { int u = __shfl_up(s, d, 64); if (lane >= d) s += u; }
    if (t == 63) w0tot = s;
    __syncthreads();
    if (wid == 1) s += w0tot;
    if (t < 98) bexcl[t] = s - v;
}

__global__ __launch_bounds__(1024) void k_scanC(const int* __restrict__ hist,
                                                const int* __restrict__ bexcl,
                                                int* __restrict__ offs,
                                                int* __restrict__ cursor) {
    __shared__ int ws[16];
    int b = blockIdx.x;
    int i = b * 1024 + threadIdx.x;
    int lane = threadIdx.x & 63, wid = threadIdx.x >> 6;
    int v = (i < NN) ? hist[i] : 0;
    int s = v;
    #pragma unroll
    for (int d = 1; d < 64; d <<= 1) { int u = __shfl_up(s, d, 64); if (lane >= d) s += u; }
    if (lane == 63) ws[wid] = s;
    __syncthreads();
    if (wid == 0) {
        int u2 = (lane < 16) ? ws[lane] : 0;
        #pragma unroll
        for (int d = 1; d < 16; d <<= 1) { int uu = __shfl_up(u2, d, 64); if (lane >= d) u2 += uu; }
        if (lane < 16) ws[lane] = u2;
    }
    __syncthreads();
    int incl = s + (wid ? ws[wid - 1] : 0) + bexcl[b];
    if (i < NN) { offs[i + 1] = incl; cursor[i] = incl - v; }
    if (i == 0) offs[0] = 0;
}

// scatter + conv1 edge weights: es2[pos] = {w01, w23 (bf16x4), src|(dst&31)<<25, ea}
__global__ void k_scatter(const int* __restrict__ src, const int* __restrict__ dst,
                          const float* __restrict__ ea,
                          const float* __restrict__ a_src1, const float* __restrict__ a_dst1,
                          const float* __restrict__ cb,
                          int* __restrict__ cursor, int4* __restrict__ es2) {
    int e = blockIdx.x * 256 + threadIdx.x;
    if (e >= NE) return;
    int s = src[e], d = dst[e];
    float eav = ea[e];
    int pos = atomicAdd(&cursor[d], 1);
    float4 as_ = *(const float4*)(a_src1 + s * 4);
    float4 ad_ = *(const float4*)(a_dst1 + d * 4);
    float lg0 = as_.x + ad_.x + eav * cb[56];
    float lg1 = as_.y + ad_.y + eav * cb[57];
    float lg2 = as_.z + ad_.z + eav * cb[58];
    float lg3 = as_.w + ad_.w + eav * cb[59];
    lg0 = lg0 >= 0.f ? lg0 : 0.2f * lg0;
    lg1 = lg1 >= 0.f ? lg1 : 0.2f * lg1;
    lg2 = lg2 >= 0.f ? lg2 : 0.2f * lg2;
    lg3 = lg3 >= 0.f ? lg3 : 0.2f * lg3;
    unsigned w01 = (unsigned)f2bf(__expf(lg0)) | ((unsigned)f2bf(__expf(lg1)) << 16);
    unsigned w23 = (unsigned)f2bf(__expf(lg2)) | ((unsigned)f2bf(__expf(lg3)) << 16);
    es2[pos] = make_int4((int)w01, (int)w23, s | ((d & 31) << 25), __float_as_int(eav));
}

// fused conv1: packed-LDS two-phase segmented reduce -> h -> MFMA (xh2 + a_src2/a_dst2)
__global__ __launch_bounds__(256, 5) void k_conv1red(
    const uint4* __restrict__ xpack, const float* __restrict__ W1, const float* __restrict__ b1,
    const int* __restrict__ offs, const int4* __restrict__ es2,
    const float* __restrict__ as2, const float* __restrict__ ad2,
    const unsigned short* __restrict__ W2fr,
    unsigned short* __restrict__ xh2b, float* __restrict__ a_src2, float* __restrict__ a_dst2) {
    __shared__ int soffs[33];
    __shared__ float sacc[32], dacc[32];
    __shared__ __attribute__((aligned(16))) uint4 xs[256];   // packed bf16 x8 per edge
    __shared__ __attribute__((aligned(8)))  uint2 wsx[256];  // packed bf16 w4 per edge
    __shared__ float ms[32][33];
    __shared__ __attribute__((aligned(16))) unsigned short hs[32][264];
    int t = threadIdx.x, lane = t & 63, wid = t >> 6;
    int n0 = blockIdx.x * 32;
    if (t <= 32) soffs[t] = offs[n0 + t];
    if (t < 32) { sacc[t] = 0.f; dacc[t] = 0.f; }
    float w1r[7][4], b1r[4];
    #pragma unroll
    for (int k = 0; k < 7; ++k)
        #pragma unroll
        for (int h = 0; h < 4; ++h) w1r[k][h] = W1[k * 256 + h * 64 + lane];
    #pragma unroll
    for (int h = 0; h < 4; ++h) b1r[h] = b1[h * 64 + lane];
    __syncthreads();
    int E0 = soffs[0], E1 = soffs[32];
    int g = t >> 3, q = t & 7;
    int go0 = soffs[g], go1 = soffs[g + 1];
    int qh = q >> 1;
    int xsl = (q & 1) ? 0 : 16;    // shift to put selected bf16 in high half
    float mh0 = 0.f, mh1 = 0.f, mh2 = 0.f, mh3 = 0.f;
    for (int C0 = E0; C0 < E1; C0 += 256) {
        int C1 = min(C0 + 256, E1);
        int j = C0 + t;
        if (j < C1) {
            int4 e4 = es2[j];
            xs[t] = xpack[e4.z & SRCMASK];
            wsx[t] = make_uint2((unsigned)e4.x, (unsigned)e4.y);
        }
        __syncthreads();
        int lo = max(go0, C0) - C0, hi = min(go1, C1) - C0;
        for (int jj = lo; jj < hi; ++jj) {
            unsigned xu = ((const unsigned*)&xs[jj])[qh];
            float xv = __uint_as_float((xu << xsl) & 0xFFFF0000u);
            uint2 wv = wsx[jj];
            mh0 = fmaf(bflo(wv.x), xv, mh0);
            mh1 = fmaf(bfhi(wv.x), xv, mh1);
            mh2 = fmaf(bflo(wv.y), xv, mh2);
            mh3 = fmaf(bfhi(wv.y), xv, mh3);
        }
        __syncthreads();
    }
    ms[g][0 * 8 + q] = mh0; ms[g][1 * 8 + q] = mh1;
    ms[g][2 * 8 + q] = mh2; ms[g][3 * 8 + q] = mh3;
    __syncthreads();
    // finish: 8 nodes per wave, lane = channel
    for (int gi = wid * 8; gi < wid * 8 + 8; ++gi) {
        bool has = soffs[gi + 1] > soffs[gi];
        #pragma unroll
        for (int h = 0; h < 4; ++h) {
            float rz = __builtin_amdgcn_rcpf(ms[gi][h * 8 + 7]);
            float a = 0.f;
            #pragma unroll
            for (int k = 0; k < 7; ++k) a = fmaf(ms[gi][h * 8 + k], w1r[k][h], a);
            float mm = (has ? a * rz : 0.f) + b1r[h];
            float hv = mm > 0.f ? mm : (__expf(mm) - 1.f);
            hs[gi][h * 64 + lane] = f2bf(hv);
        }
    }
    __syncthreads();
    // MFMA: 2 node-tiles x 4 col-tiles; epilogue computes a_src2/a_dst2 from acc
    int row = lane & 15, kg = lane >> 4;
    #pragma unroll
    for (int u = wid; u < 8; u += 4) {
        int nt = u & 1, ct = u >> 1;
        f32x4 acc = {0.f, 0.f, 0.f, 0.f};
        #pragma unroll
        for (int ks = 0; ks < 8; ++ks) {
            bf16x8 av = *(const bf16x8*)&hs[nt * 16 + row][ks * 32 + kg * 8];
            bf16x8 bv = *(const bf16x8*)(W2fr + (((ks * 4 + ct) * 64) + lane) * 8);
            acc = __builtin_amdgcn_mfma_f32_16x16x32_bf16(av, bv, acc, 0, 0, 0);
        }
        float as2v = as2[ct * 16 + row];
        float ad2v = ad2[ct * 16 + row];
        #pragma unroll
        for (int i = 0; i < 4; ++i) {
            xh2b[(n0 + nt * 16 + kg * 4 + i) * 64 + ct * 16 + row] = f2bf(acc[i]);
            float ps = acc[i] * as2v;
            float pd = acc[i] * ad2v;
            #pragma unroll
            for (int o = 1; o < 16; o <<= 1) {
                ps += __shfl_xor(ps, o, 64);
                pd += __shfl_xor(pd, o, 64);
            }
            if (row == 0) {
                atomicAdd(&sacc[nt * 16 + kg * 4 + i], ps);
                atomicAdd(&dacc[nt * 16 + kg * 4 + i], pd);
            }
        }
    }
    __syncthreads();
    if (t < 32) {
        a_src2[n0 + t] = sacc[t];
        a_dst2[n0 + t] = dacc[t];
    }
}

// fused conv2 normalization over sorted runs: z reduce + cs[src][cluster(dst)] += ew/z
__global__ __launch_bounds__(256) void k_znorm(
    const int4* __restrict__ es2, const int* __restrict__ offs,
    const float* __restrict__ a_src2, const float* __restrict__ a_dst2,
    const int* __restrict__ assign, const float* __restrict__ cb,
    float* __restrict__ cs) {
    int t = threadIdx.x, lane = t & 63, wid = t >> 6;
    int g = lane >> 3, q = lane & 7;
    int n = (blockIdx.x * 4 + wid) * 8 + g;
    int o0 = offs[n], o1 = offs[n + 1];
    float adn = a_dst2[n];
    float c2 = cb[60];
    float z = 0.f;
    int s0 = 0; float ew0 = 0.f; bool v0 = false;
    for (int j = o0 + q; j < o1; j += 8) {
        int4 se = es2[j];
        int sx = se.z & SRCMASK;
        float lg = a_src2[sx] + adn + __int_as_float(se.w) * c2;
        lg = lg >= 0.f ? lg : 0.2f * lg;
        float ew = __expf(lg);
        if (!v0) { s0 = sx; ew0 = ew; v0 = true; }
        z += ew;
    }
    z += __shfl_xor(z, 1, 64);
    z += __shfl_xor(z, 2, 64);
    z += __shfl_xor(z, 4, 64);
    float rz = __builtin_amdgcn_rcpf(z);   // no edges -> no adds below
    int c = assign[n];
    if (v0) atomicAdd(&cs[s0 * 4 + c], ew0 * rz);
    for (int j = o0 + q + 8; j < o1; j += 8) {
        int4 se = es2[j];
        int sx = se.z & SRCMASK;
        float lg = a_src2[sx] + adn + __int_as_float(se.w) * c2;
        lg = lg >= 0.f ? lg : 0.2f * lg;
        atomicAdd(&cs[sx * 4 + c], __expf(lg) * rz);
    }
}

// pooling as tiny GEMM: 8 lanes/node, 16B loads, register accumulators, direct gacc atomics
__global__ __launch_bounds__(256) void k_pool(
    const unsigned short* __restrict__ xh2b, const float* __restrict__ cs,
    const int* __restrict__ assign, const float* __restrict__ x,
    float* __restrict__ gacc) {
    __shared__ float csum[264];
    int t = threadIdx.x;
    int q = t & 7, slot = t >> 3;             // 32 node-slots per block
    float a0[8], a1[8], a2[8], a3[8];
    #pragma unroll
    for (int j = 0; j < 8; ++j) { a0[j] = 0.f; a1[j] = 0.f; a2[j] = 0.f; a3[j] = 0.f; }
    float cnt0 = 0.f, cnt1 = 0.f, cnt2 = 0.f, cnt3 = 0.f;
    float cf0 = 0.f, cf1 = 0.f, cf2 = 0.f, cf3 = 0.f;
    for (int n = blockIdx.x * 32 + slot; n < NN; n += NPB * 32) {
        uint4 u = *(const uint4*)(xh2b + n * 64 + q * 8);
        float4 c4 = *(const float4*)(cs + n * 4);
        float xv[8];
        xv[0] = bf2f((unsigned short)u.x); xv[1] = bf2f((unsigned short)(u.x >> 16));
        xv[2] = bf2f((unsigned short)u.y); xv[3] = bf2f((unsigned short)(u.y >> 16));
        xv[4] = bf2f((unsigned short)u.z); xv[5] = bf2f((unsigned short)(u.z >> 16));
        xv[6] = bf2f((unsigned short)u.w); xv[7] = bf2f((unsigned short)(u.w >> 16));
        #pragma unroll
        for (int j = 0; j < 8; ++j) {
            a0[j] = fmaf(c4.x, xv[j], a0[j]);
            a1[j] = fmaf(c4.y, xv[j], a1[j]);
            a2[j] = fmaf(c4.z, xv[j], a2[j]);
            a3[j] = fmaf(c4.w, xv[j], a3[j]);
        }
        if (q == 0) {
            int a = assign[n];
            float xf = x[n * 7 + 6];
            cnt0 += (a == 0) ? 1.f : 0.f;  cf0 += (a == 0) ? xf : 0.f;
            cnt1 += (a == 1) ? 1.f : 0.f;  cf1 += (a == 1) ? xf : 0.f;
            cnt2 += (a == 2) ? 1.f : 0.f;  cf2 += (a == 2) ? xf : 0.f;
            cnt3 += (a == 3) ? 1.f : 0.f;  cf3 += (a == 3) ? xf : 0.f;
        }
    }
    for (int i = t; i < 264; i += 256) csum[i] = 0.f;
    __syncthreads();
    int base = q * 8;
    #pragma unroll
    for (int j = 0; j < 8; ++j) {
        atomicAdd(&csum[0 * 64 + base + j], a0[j]);
        atomicAdd(&csum[1 * 64 + base + j], a1[j]);
        atomicAdd(&csum[2 * 64 + base + j], a2[j]);
        atomicAdd(&csum[3 * 64 + base + j], a3[j]);
    }
    if (q == 0) {
        atomicAdd(&csum[256], cnt0); atomicAdd(&csum[257], cnt1);
        atomicAdd(&csum[258], cnt2); atomicAdd(&csum[259], cnt3);
        atomicAdd(&csum[260], cf0);  atomicAdd(&csum[261], cf1);
        atomicAdd(&csum[262], cf2);  atomicAdd(&csum[263], cf3);
    }
    __syncthreads();
    for (int i = t; i < 264; i += 256) atomicAdd(&gacc[i], csum[i]);
}

// final head (256 threads): cluster means (+cnt*b2), actor MLP + softmax, critic MLP
__global__ __launch_bounds__(256) void k_head(
    const float* __restrict__ gacc, const float* __restrict__ b2,
    const float* __restrict__ A1, const float* __restrict__ ba1,
    const float* __restrict__ A2, const float* __restrict__ ba2,
    const float* __restrict__ C1, const float* __restrict__ bc1,
    const float* __restrict__ C2, const float* __restrict__ bc2,
    float* __restrict__ out) {
    __shared__ float zc[4][64];
    __shared__ float cfs[4];
    __shared__ float logits[4];
    __shared__ float vpart[4][64];
    int t = threadIdx.x;
    int j = t & 63, wv = t >> 6;   // wave wv handles cluster wv
    float cnt = gacc[256 + wv];
    float den = fmaxf(cnt, 1.f);
    zc[wv][j] = (cnt > 0.f) ? (gacc[wv * 64 + j] + cnt * b2[j]) / den : 0.f;
    if (t < 4) {
        float cc = gacc[256 + t];
        cfs[t] = (cc > 0.f) ? gacc[260 + t] / fmaxf(cc, 1.f) : 0.f;
    }
    __syncthreads();
    // actor: cluster wv
    float tv = ba1[j];
    for (int k = 0; k < 64; ++k) tv = fmaf(zc[wv][k], A1[k * 64 + j], tv);
    tv = fmaf(cfs[wv], A1[64 * 64 + j], tv);
    tv = fmaxf(tv, 0.f);
    float sred = wave_reduce_sum(tv * A2[j]);
    if (j == 0) logits[wv] = sred + ba2[0];
    // critic partials: wave wv covers k in [wv*64, (wv+1)*64)
    float vj = (wv == 0) ? bc1[j] : 0.f;
    for (int kk = 0; kk < 64; ++kk) vj = fmaf(zc[wv][kk], C1[(wv * 64 + kk) * 64 + j], vj);
    vpart[wv][j] = vj;
    __syncthreads();
    if (wv == 0) {
        float vv = fmaxf(vpart[0][j] + vpart[1][j] + vpart[2][j] + vpart[3][j], 0.f);
        float v = wave_reduce_sum(vv * C2[j]);
        if (j == 0) {
            float m = fmaxf(fmaxf(logits[0], logits[1]), fmaxf(logits[2], logits[3]));
            float e0 = __expf(logits[0] - m), e1 = __expf(logits[1] - m);
            float e2 = __expf(logits[2] - m), e3 = __expf(logits[3] - m);
            float sum = e0 + e1 + e2 + e3;
            out[0] = e0 / sum; out[1] = e1 / sum; out[2] = e2 / sum; out[3] = e3 / sum;
            out[4] = v + bc2[0];
        }
    }
    out[5 + wv * 64 + j] = zc[wv][j];
}

extern "C" void kernel_launch(void* const* d_in, const int* in_sizes, int n_in,
                              void* d_out, int out_size, void* d_ws, size_t ws_size,
                              hipStream_t stream) {
    const float* x    = (const float*)d_in[0];
    const int*   ei   = (const int*)d_in[1];
    const float* ea   = (const float*)d_in[2];
    const int*   asg  = (const int*)d_in[3];
    const float* W1   = (const float*)d_in[4];
    const float* as1  = (const float*)d_in[5];
    const float* ad1  = (const float*)d_in[6];
    const float* We1  = (const float*)d_in[7];
    const float* ae1  = (const float*)d_in[8];
    const float* b1   = (const float*)d_in[9];
    const float* W2   = (const float*)d_in[10];
    const float* as2  = (const float*)d_in[11];
    const float* ad2  = (const float*)d_in[12];
    const float* We2  = (const float*)d_in[13];
    const float* ae2  = (const float*)d_in[14];
    const float* b2   = (const float*)d_in[15];
    const float* A1   = (const float*)d_in[16];
    const float* ba1  = (const float*)d_in[17];
    const float* A2   = (const float*)d_in[18];
    const float* ba2  = (const float*)d_in[19];
    const float* C1   = (const float*)d_in[20];
    const float* bc1  = (const float*)d_in[21];
    const float* C2   = (const float*)d_in[22];
    const float* bc2  = (const float*)d_in[23];
    const int* src = ei;
    const int* dst = ei + NE;

    char* w = (char*)d_ws;
    size_t off = 0;
    auto alloc = [&](size_t bytes) -> void* {
        void* p = w + off;
        off += (bytes + 255) & ~(size_t)255;
        return p;
    };
    // contiguous zero-init region: hist | cs | gacc
    int*   hist   = (int*)alloc(NN * sizeof(int));
    float* cs     = (float*)alloc(NN * 4 * sizeof(float));
    float* gacc   = (float*)alloc(264 * sizeof(float));
    size_t zspan  = (size_t)((char*)gacc + 264 * sizeof(float) - (char*)hist);
    float* a_src1 = (float*)alloc(NN * 4 * sizeof(float));
    float* a_dst1 = (float*)alloc(NN * 4 * sizeof(float));
    float* a_src2 = (float*)alloc(NN * sizeof(float));
    float* a_dst2 = (float*)alloc(NN * sizeof(float));
    uint4* xpack  = (uint4*)alloc(NN * sizeof(uint4));
    int*   offs   = (int*)alloc((NN + 1) * sizeof(int));
    int*   cursor = (int*)alloc(NN * sizeof(int));
    int*   bsum   = (int*)alloc(128 * sizeof(int));
    int*   bexcl  = (int*)alloc(128 * sizeof(int));
    int4*  es2    = (int4*)alloc(NE * sizeof(int4));
    unsigned short* xh2b = (unsigned short*)alloc(NN * 64 * sizeof(unsigned short));
    unsigned short* W2fr = (unsigned short*)alloc(16384 * sizeof(unsigned short));
    float* cb     = (float*)alloc(64 * sizeof(float));
    (void)ws_size; (void)n_in; (void)in_sizes; (void)out_size;

    hipMemsetAsync(hist, 0, zspan, stream);

    k_pre<<<65, 256, 0, stream>>>(W1, as1, ad1, We1, ae1, We2, ae2, W2, cb, W2fr);
    k_node1h<<<(NN + 255) / 256, 256, 0, stream>>>(x, cb, dst, a_src1, a_dst1, xpack, hist);
    k_scanA<<<98, 1024, 0, stream>>>(hist, bsum);
    k_scanB<<<1, 128, 0, stream>>>(bsum, bexcl);
    k_scanC<<<98, 1024, 0, stream>>>(hist, bexcl, offs, cursor);
    k_scatter<<<(NE + 255) / 256, 256, 0, stream>>>(src, dst, ea, a_src1, a_dst1, cb,
                                                    cursor, es2);
    k_conv1red<<<NN / 32, 256, 0, stream>>>(xpack, W1, b1, offs, es2,
                                            as2, ad2, W2fr, xh2b, a_src2, a_dst2);
    k_znorm<<<NN / 32, 256, 0, stream>>>(es2, offs, a_src2, a_dst2, asg, cb, cs);
    k_pool<<<NPB, 256, 0, stream>>>(xh2b, cs, asg, x, gacc);
    k_head<<<1, 256, 0, stream>>>(gacc, b2, A1, ba1, A2, ba2, C1, bc1, C2, bc2, (float*)d_out);
}